// Round 14
// baseline (373.240 us; speedup 1.0000x reference)
//
#include <hip/hip_runtime.h>
#include <math.h>

#define BB 2
#define TT 24
#define DD 32
#define HWp 4096            // 64*64
#define NN (BB*TT)          // 48
#define PIX (NN*HWp)        // 196608
#define C2 (2*DD)           // 64

// d_out offsets (floats)
#define MAIN_RE 0
#define MAIN_IM (NN*DD*HWp)              // 6291456
#define HOUT_RE (2*NN*DD*HWp)            // 12582912
#define HOUT_IM (HOUT_RE + BB*HWp*DD)    // 12845056
#define FLUX_RE (HOUT_RE + 2*BB*HWp*DD)  // 13107200
#define FLUX_IM (FLUX_RE + BB*DD)        // 13107264

// ws offsets (floats)
#define WS_XN   0                        // PIX*64 (bf16 xn for conv)
#define WS_XE   (WS_XN + PIX*C2)         // PIX*64  xe -> u planes
#define WS_G1   (WS_XE + PIX*C2)         // PIX*32  g1 planes
#define WS_G2   (WS_G1 + PIX*DD)         // PIX*32  spg planes
#define WS_WINV (WS_G2 + PIX*DD)         // 2048 f32
#define WS_SUMS (WS_WINV + 2048)         // 3072 (unused)
#define WS_GATE (WS_SUMS + 3072)         // 1536
#define WS_SRCR (WS_GATE + 1536)
#define WS_SRCI (WS_SRCR + 1536)
#define WS_ODR  (WS_SRCI + 1536)
#define WS_ODI  (WS_ODR + 1536)
#define WS_OFR  (WS_ODI + 1536)
#define WS_OFI  (WS_OFR + 1536)
#define WS_WPK  (WS_OFI + 1536)          // 36864 ushorts = 18432 floats
#define WS_PART (WS_WPK + 18432)         // 48*16*64 floats
#define WS_WE   (WS_PART + 49152)        // 2048 u32 eig weights [64][32]
#define WS_SG   (WS_WE + 2048)           // 1024 u32 sg1 weights [32][32]
#define WS_WIB  (WS_SG + 1024)           // 2048 u32 Winv packed [64][32]
#define WS_W1B  (WS_WIB + 2048)          // 4096 u32 ffn w1 packed [128][32]
#define WS_W2B  (WS_W1B + 4096)          // 4096 u32 ffn w2 packed [64][64]

typedef __attribute__((ext_vector_type(8))) short bf16x8;
typedef __attribute__((ext_vector_type(4))) float f32x4;
union FU { unsigned u[4]; bf16x8 f; };
union FU4 { uint4 v; unsigned u[4]; bf16x8 f; };

__device__ __forceinline__ float sigmoidf_(float x) { return 1.f / (1.f + expf(-x)); }
__device__ __forceinline__ float softplusf_(float x) { return log1pf(expf(x)); }
__device__ __forceinline__ unsigned short f2bf(float f) {
  unsigned u = __float_as_uint(f);
  return (unsigned short)((u + 0x7FFFu + ((u >> 16) & 1u)) >> 16);   // RNE
}
__device__ __forceinline__ unsigned pk2(float lo, float hi) {
  return (unsigned)f2bf(lo) | ((unsigned)f2bf(hi) << 16);
}

// ---------------- Gauss-Jordan inverse of Wb (32x32 complex) + bf16 B-frag pack ----------
__global__ void k_invert(const float* __restrict__ Wre, const float* __restrict__ Wim,
                         float* __restrict__ ws) {
  __shared__ float Mre[32][64];
  __shared__ float Mim[32][64];
  __shared__ float fre[32], fim[32];
  __shared__ float pr_s, pi_s;
  __shared__ int piv_s;
  int tid = threadIdx.x;  // 256 threads
  for (int idx = tid; idx < 2048; idx += 256) {
    int i = idx >> 6, j = idx & 63;
    if (j < 32) { Mre[i][j] = Wre[i * 32 + j]; Mim[i][j] = Wim[i * 32 + j]; }
    else        { Mre[i][j] = (j - 32 == i) ? 1.f : 0.f; Mim[i][j] = 0.f; }
  }
  __syncthreads();
  for (int k = 0; k < 32; ++k) {
    if (tid == 0) {
      int best = k; float bm = fabsf(Mre[k][k]) + fabsf(Mim[k][k]);
      for (int r = k + 1; r < 32; ++r) {
        float m = fabsf(Mre[r][k]) + fabsf(Mim[r][k]);
        if (m > bm) { bm = m; best = r; }
      }
      piv_s = best;
    }
    __syncthreads();
    int pv = piv_s;
    if (pv != k && tid < 64) {
      float tr = Mre[k][tid], ti = Mim[k][tid];
      Mre[k][tid] = Mre[pv][tid]; Mim[k][tid] = Mim[pv][tid];
      Mre[pv][tid] = tr; Mim[pv][tid] = ti;
    }
    __syncthreads();
    if (tid == 0) {
      float a = Mre[k][k], b = Mim[k][k];
      float d = a * a + b * b;
      pr_s = a / d; pi_s = -b / d;
    }
    __syncthreads();
    float pr = pr_s, pi = pi_s;
    if (tid < 64) {
      float a = Mre[k][tid], b = Mim[k][tid];
      Mre[k][tid] = a * pr - b * pi;
      Mim[k][tid] = a * pi + b * pr;
    }
    __syncthreads();
    if (tid < 32) { fre[tid] = Mre[tid][k]; fim[tid] = Mim[tid][k]; }
    __syncthreads();
    for (int idx = tid; idx < 2048; idx += 256) {
      int i = idx >> 6, j = idx & 63;
      if (i != k) {
        float fr = fre[i], fi = fim[i];
        float ar = Mre[k][j], ai = Mim[k][j];
        Mre[i][j] -= fr * ar - fi * ai;
        Mim[i][j] -= fr * ai + fi * ar;
      }
    }
    __syncthreads();
  }
  for (int idx = tid; idx < 1024; idx += 256) {
    int e = idx >> 5, d = idx & 31;
    ws[WS_WINV + e * 32 + d] = Mre[e][32 + d];
    ws[WS_WINV + 1024 + e * 32 + d] = Mim[e][32 + d];
  }
  unsigned* wib = (unsigned*)(ws + WS_WIB);
  for (int idx = tid; idx < 2048; idx += 256) {
    int j = idx >> 5, kp = idx & 31;
    float v[2];
#pragma unroll
    for (int h = 0; h < 2; ++h) {
      int k = 2 * kp + h;
      float x;
      if (j < 32) x = (k < 32) ? Mre[k][32 + j] : -Mim[k - 32][32 + j];
      else        x = (k < 32) ? Mim[k][32 + (j - 32)] : Mre[k - 32][32 + (j - 32)];
      v[h] = x;
    }
    wib[idx] = pk2(v[0], v[1]);
  }
}

// ---------------- weight pre-pack: wpack[tap][oc][ci] bf16 <- conv_w[oc][ci][tap] f32 ----
__global__ void k_wprep(const float* __restrict__ w, unsigned short* __restrict__ wpk) {
  int idx = blockIdx.x * 256 + threadIdx.x;
  if (idx >= 9 * 64 * 64) return;
  int tap = idx >> 12;
  int rem = idx & 4095;
  int oc = rem >> 6, ci = rem & 63;
  wpk[idx] = f2bf(w[(oc * 64 + ci) * 9 + tap]);
}

// ---------------- eig + sg1 weight pre-pack (bf16 [N][Kpair] B-fragment layout) ----------
__global__ void k_eprep(const float* __restrict__ Wre, const float* __restrict__ Wim,
                        const float* __restrict__ sgw1,
                        unsigned* __restrict__ we, unsigned* __restrict__ sg) {
  int idx = blockIdx.x * 256 + threadIdx.x;
  if (idx < 2048) {
    int j = idx >> 5, kp = idx & 31;
    float v[2];
#pragma unroll
    for (int h = 0; h < 2; ++h) {
      int k = 2 * kp + h;
      float x;
      if (j < 32) x = (k < 32) ? Wre[k * 32 + j] : -Wim[(k - 32) * 32 + j];
      else        x = (k < 32) ? Wim[k * 32 + (j - 32)] : Wre[(k - 32) * 32 + (j - 32)];
      v[h] = x;
    }
    we[idx] = pk2(v[0], v[1]);
  }
  if (idx < 1024) {
    int oc = idx >> 5, kp = idx & 31;
    sg[idx] = pk2(sgw1[oc * 64 + 2 * kp], sgw1[oc * 64 + 2 * kp + 1]);
  }
}

// ---------------- ffn weight pre-pack: w1 [128][32] u32, w2 [64][64] u32 ----------------
__global__ void k_fprep(const float* __restrict__ w1, const float* __restrict__ w2,
                        unsigned* __restrict__ w1b, unsigned* __restrict__ w2b) {
  int idx = blockIdx.x * 256 + threadIdx.x;
  if (idx >= 4096) return;
  {
    int hid = idx >> 5, kp = idx & 31;
    w1b[idx] = pk2(w1[(2 * kp) * 128 + hid], w1[(2 * kp + 1) * 128 + hid]);
  }
  {
    int o = idx >> 6, kp = idx & 63;
    w2b[idx] = pk2(w2[(2 * kp) * 64 + o], w2[(2 * kp + 1) * 64 + o]);
  }
}

// ---------------- spatial LayerNorm -> xn bf16 channels-last [n][pix][64] ----------------
__global__ void k_ln_s(const float* __restrict__ xre, const float* __restrict__ xim,
                       const float* __restrict__ g, const float* __restrict__ b,
                       float* __restrict__ ws) {
  int gid = blockIdx.x * 256 + threadIdx.x;
  if (gid >= PIX) return;
  int n = gid >> 12, p = gid & 4095;
  float v[64];
  float s = 0.f;
#pragma unroll
  for (int c = 0; c < 32; ++c) { v[c] = xre[(n * 32 + c) * 4096 + p]; s += v[c]; }
#pragma unroll
  for (int c = 0; c < 32; ++c) { v[32 + c] = xim[(n * 32 + c) * 4096 + p]; s += v[32 + c]; }
  float m = s * (1.f / 64.f);
  float vs = 0.f;
#pragma unroll
  for (int c = 0; c < 64; ++c) { float d = v[c] - m; vs += d * d; }
  float rs = rsqrtf(vs * (1.f / 64.f) + 1e-5f);
#pragma unroll
  for (int c = 0; c < 64; ++c) v[c] = (v[c] - m) * rs * g[c] + b[c];
  uint4* dst = (uint4*)ws + gid * 8;
#pragma unroll
  for (int q = 0; q < 8; ++q) {
    uint4 u;
    u.x = pk2(v[q * 8 + 0], v[q * 8 + 1]);
    u.y = pk2(v[q * 8 + 2], v[q * 8 + 3]);
    u.z = pk2(v[q * 8 + 4], v[q * 8 + 5]);
    u.w = pk2(v[q * 8 + 6], v[q * 8 + 7]);
    dst[q] = u;
  }
}

// ---------------- 3x3 conv 64->64 as 9 shifted bf16 MFMA GEMMs ----------------
__global__ void __launch_bounds__(256) k_conv(
    const unsigned* __restrict__ xnb_u, const unsigned short* __restrict__ wpk,
    const float* __restrict__ bconv,
    const float* __restrict__ xre, const float* __restrict__ xim,
    float* __restrict__ out) {
  __shared__ unsigned xls[6 * 66 * 36];
  int bid = blockIdx.x;
  int n = bid >> 4;
  int y0 = (bid & 15) * 4;
  int tid = threadIdx.x;
  int wv = tid >> 6, l = tid & 63;
  int l15 = l & 15, l4 = l >> 4;

  const uint4* xnb4 = (const uint4*)xnb_u;
  for (int idx = tid; idx < 396; idx += 256) {
    int r = idx / 66, c = idx - r * 66;
    int y = y0 - 1 + r, x = c - 1;
    bool valid = ((unsigned)y < 64u) & ((unsigned)x < 64u);
    int pg = n * 4096 + y * 64 + x;
    uint4 z; z.x = z.y = z.z = z.w = 0u;
#pragma unroll
    for (int q = 0; q < 8; ++q) {
      uint4 v = valid ? xnb4[pg * 8 + q] : z;
      *(uint4*)&xls[idx * 36 + q * 4] = v;
    }
  }
  __syncthreads();

  f32x4 acc[4][4];
#pragma unroll
  for (int Nt = 0; Nt < 4; ++Nt) {
    float bb = bconv[Nt * 16 + l15];
#pragma unroll
    for (int mt = 0; mt < 4; ++mt) acc[mt][Nt] = (f32x4){bb, bb, bb, bb};
  }

  const uint4* wq = (const uint4*)wpk;
#pragma unroll
  for (int tap = 0; tap < 9; ++tap) {
    int ky = tap / 3, kx = tap - ky * 3;
    int rowbase = (wv + ky) * 66 + kx + l15;
#pragma unroll
    for (int ks = 0; ks < 2; ++ks) {
      FU4 B[4];
#pragma unroll
      for (int Nt = 0; Nt < 4; ++Nt)
        B[Nt].v = wq[tap * 512 + (Nt * 16 + l15) * 8 + ks * 4 + l4];
#pragma unroll
      for (int mt = 0; mt < 4; ++mt) {
        FU4 A;
        A.v = *(const uint4*)&xls[(rowbase + mt * 16) * 36 + ks * 16 + l4 * 4];
#pragma unroll
        for (int Nt = 0; Nt < 4; ++Nt)
          acc[mt][Nt] = __builtin_amdgcn_mfma_f32_16x16x32_bf16(A.f, B[Nt].f, acc[mt][Nt], 0, 0, 0);
      }
    }
  }

#pragma unroll
  for (int Nt = 0; Nt < 4; ++Nt) {
    int oc = Nt * 16 + l15;
    int d = oc & 31;
    const float* resid = (oc < 32) ? xre : xim;
    float* dst = out + ((oc < 32) ? MAIN_RE : MAIN_IM) + (n * 32 + d) * 4096;
    const float* rsd = resid + (n * 32 + d) * 4096;
#pragma unroll
    for (int mt = 0; mt < 4; ++mt) {
      int pixbase = (y0 + wv) * 64 + mt * 16 + l4 * 4;
#pragma unroll
      for (int r = 0; r < 4; ++r)
        dst[pixbase + r] = rsd[pixbase + r] + acc[mt][Nt][r];
    }
  }
}

// ---------------- x_eig v3: MFMA dual-GEMM, weights from global (L2-hot) -----------------
// LDS: xp[64][35] + xef[64][67] = 25.5KB -> 6 blocks/CU. Strides 35/67 kill bank conflicts.
__global__ void __launch_bounds__(256) k_xeig(
    const float* __restrict__ out, const unsigned* __restrict__ weP,
    const unsigned* __restrict__ sgP, float* __restrict__ xe,
    float* __restrict__ g1, const float* __restrict__ sgb1,
    float* __restrict__ part) {
  __shared__ unsigned xp[64][35];
  __shared__ float xef[64][67];

  int tid = threadIdx.x;
  int gbase = blockIdx.x * 256;
  int l = tid & 63, wv = tid >> 6;
  int l15 = l & 15, l4 = l >> 4;
  int p64 = l, q = wv;
  const uint4* we4 = (const uint4*)weP;   // [64 rows][8 uint4]
  const uint4* sg4 = (const uint4*)sgP;   // [32 rows][8 uint4]

  float ssum[16];
#pragma unroll
  for (int i = 0; i < 16; ++i) ssum[i] = 0.f;

  for (int ph = 0; ph < 4; ++ph) {
    int gg = gbase + ph * 64 + p64;
    int n = gg >> 12, p = gg & 4095;

    float xv[16];
#pragma unroll
    for (int i = 0; i < 16; ++i) {
      int c = q * 16 + i;
      xv[i] = (c < 32) ? out[MAIN_RE + (n * 32 + c) * 4096 + p]
                       : out[MAIN_IM + (n * 32 + (c - 32)) * 4096 + p];
    }
#pragma unroll
    for (int ii = 0; ii < 8; ++ii)
      xp[p64][q * 8 + ii] = pk2(xv[2 * ii], xv[2 * ii + 1]);
    __syncthreads();   // A

    int arow = wv * 16 + l15;
    FU a0, a1;
#pragma unroll
    for (int jj = 0; jj < 4; ++jj) {
      a0.u[jj] = xp[arow][l4 * 4 + jj];
      a1.u[jj] = xp[arow][16 + l4 * 4 + jj];
    }
#pragma unroll
    for (int Nt = 0; Nt < 4; ++Nt) {
      f32x4 acc = (f32x4){0.f, 0.f, 0.f, 0.f};
      FU4 b0f, b1f;
      int brow = Nt * 16 + l15;
      b0f.v = we4[brow * 8 + l4];
      b1f.v = we4[brow * 8 + 4 + l4];
      acc = __builtin_amdgcn_mfma_f32_16x16x32_bf16(a0.f, b0f.f, acc, 0, 0, 0);
      acc = __builtin_amdgcn_mfma_f32_16x16x32_bf16(a1.f, b1f.f, acc, 0, 0, 0);
#pragma unroll
      for (int r = 0; r < 4; ++r)
        xef[wv * 16 + l4 * 4 + r][Nt * 16 + l15] = acc[r];
    }
    __syncthreads();   // B

    float xo[16];
#pragma unroll
    for (int i = 0; i < 16; ++i) {
      xo[i] = xef[p64][q * 16 + i];
      ssum[i] += xo[i];
      xe[(q * 16 + i) * PIX + gg] = xo[i];
    }
#pragma unroll
    for (int ii = 0; ii < 8; ++ii)
      xp[p64][q * 8 + ii] = pk2(xo[2 * ii], xo[2 * ii + 1]);
    __syncthreads();   // C

    FU c0, c1;
#pragma unroll
    for (int jj = 0; jj < 4; ++jj) {
      c0.u[jj] = xp[arow][l4 * 4 + jj];
      c1.u[jj] = xp[arow][16 + l4 * 4 + jj];
    }
#pragma unroll
    for (int Nt = 0; Nt < 2; ++Nt) {
      float bb = sgb1[Nt * 16 + l15];
      f32x4 acc = (f32x4){bb, bb, bb, bb};
      FU4 b0f, b1f;
      int brow = Nt * 16 + l15;
      b0f.v = sg4[brow * 8 + l4];
      b1f.v = sg4[brow * 8 + 4 + l4];
      acc = __builtin_amdgcn_mfma_f32_16x16x32_bf16(c0.f, b0f.f, acc, 0, 0, 0);
      acc = __builtin_amdgcn_mfma_f32_16x16x32_bf16(c1.f, b1f.f, acc, 0, 0, 0);
#pragma unroll
      for (int r = 0; r < 4; ++r) {
        float v = acc[r];
        xef[wv * 16 + l4 * 4 + r][Nt * 16 + l15] = v * sigmoidf_(v);
      }
    }
    __syncthreads();   // D

#pragma unroll
    for (int i = 0; i < 8; ++i)
      g1[(q * 8 + i) * PIX + gg] = xef[p64][q * 8 + i];
    __syncthreads();   // E: protect xp/xef reuse next phase
  }

#pragma unroll
  for (int i = 0; i < 16; ++i) {
    float v = ssum[i];
    v += __shfl_xor(v, 1);
    v += __shfl_xor(v, 2);
    v += __shfl_xor(v, 4);
    v += __shfl_xor(v, 8);
    v += __shfl_xor(v, 16);
    v += __shfl_xor(v, 32);
    if (l == 0) part[blockIdx.x * 64 + q * 16 + i] = v;
  }
}

// ---------------- flux scan (T=24) + all per-(b,t,d) coefficients ----------------
__global__ void k_flux(float* __restrict__ ws, float* __restrict__ out,
                       const float* __restrict__ dt_seq,
                       const float* __restrict__ flux_re, const float* __restrict__ flux_im,
                       const float* __restrict__ lam_flux,
                       const float* __restrict__ bf_re, const float* __restrict__ bf_im,
                       const float* __restrict__ c_re, const float* __restrict__ c_im,
                       const float* __restrict__ g_w, const float* __restrict__ g_b,
                       const float* __restrict__ a_decay, const float* __restrict__ b_freq) {
  int tid = threadIdx.x;
  if (tid >= 64) return;
  int b = tid >> 5, e = tid & 31;
  float sp_lf = softplusf_(lam_flux[e]);
  float lr = -softplusf_(a_decay[e]);
  float li = b_freq[e];
  float den = lr * lr + li * li;
  float bfr = bf_re[e], bfi = bf_im[e];
  float cr = c_re[e], ci = c_im[e];
  float fr = flux_re[b * 32 + e], fi = flux_im[b * 32 + e];
  const float* part = ws + WS_PART;
  for (int t = 0; t < 24; ++t) {
    int n = b * 24 + t;
    float dt = dt_seq[n];
    float A = expf(-sp_lf * dt);
    float xmr = 0.f, xmi = 0.f;
#pragma unroll
    for (int j = 0; j < 16; ++j) {
      xmr += part[(n * 16 + j) * 64 + e];
      xmi += part[(n * 16 + j) * 64 + 32 + e];
    }
    xmr *= (1.f / 4096.f);
    xmi *= (1.f / 4096.f);
    float Xr = (bfr * xmr - bfi * xmi) * dt;
    float Xi = (bfr * xmi + bfi * xmr) * dt;
    fr = A * fr + Xr;
    fi = A * fi + Xi;
    ws[WS_GATE + n * 32 + e] = sigmoidf_(fr * g_w[e] + g_b[e]);
    ws[WS_SRCR + n * 32 + e] = fr * cr - fi * ci;
    ws[WS_SRCI + n * 32 + e] = fr * ci + fi * cr;
    float er = expf(lr * dt);
    float odr = er * cosf(li * dt);
    float odi = er * sinf(li * dt);
    ws[WS_ODR + n * 32 + e] = odr;
    ws[WS_ODI + n * 32 + e] = odi;
    float nr = odr - 1.f, ni = odi;
    ws[WS_OFR + n * 32 + e] = (nr * lr + ni * li) / den;
    ws[WS_OFI + n * 32 + e] = (ni * lr - nr * li) / den;
  }
  out[FLUX_RE + b * 32 + e] = fr;
  out[FLUX_IM + b * 32 + e] = fi;
}

// ---------------- gate v3: dw 3x3 (shuffle stencil) + sg3 + sigmoid -> spg planes ---------
__global__ void __launch_bounds__(256) k_gate(
    const float* __restrict__ g1, float* __restrict__ spgP,
    const float* __restrict__ dw, const float* __restrict__ w2,
    const float* __restrict__ b2) {
  __shared__ float g2s[128][33];
  int tid = threadIdx.x;
  int l = tid & 63;
  int wv = tid >> 6;
  int r = wv >> 1, h = wv & 1;
  int pixbase = blockIdx.x * 128;
  int n = pixbase >> 12;
  int y = ((pixbase & 4095) >> 6) + r;
  int g = pixbase + r * 64 + l;
  int rp = r * 64 + l;

#pragma unroll
  for (int c = 0; c < 16; ++c) {
    int oc = h * 16 + c;
    const float* src = g1 + oc * PIX + n * 4096;
    const float* w = dw + oc * 9;        // uniform -> s_load
    float r0 = (y > 0)  ? src[(y - 1) * 64 + l] : 0.f;
    float r1 = src[y * 64 + l];
    float r2 = (y < 63) ? src[(y + 1) * 64 + l] : 0.f;
    float l0 = __shfl_up(r0, 1), t0 = __shfl_down(r0, 1);
    float l1 = __shfl_up(r1, 1), t1 = __shfl_down(r1, 1);
    float l2 = __shfl_up(r2, 1), t2 = __shfl_down(r2, 1);
    if (l == 0)  { l0 = 0.f; l1 = 0.f; l2 = 0.f; }
    if (l == 63) { t0 = 0.f; t1 = 0.f; t2 = 0.f; }
    float acc = 0.f;
    acc = fmaf(l0, w[0], acc); acc = fmaf(r0, w[1], acc); acc = fmaf(t0, w[2], acc);
    acc = fmaf(l1, w[3], acc); acc = fmaf(r1, w[4], acc); acc = fmaf(t1, w[5], acc);
    acc = fmaf(l2, w[6], acc); acc = fmaf(r2, w[7], acc); acc = fmaf(t2, w[8], acc);
    g2s[rp][oc] = acc;
  }
  __syncthreads();
  float g2a[32];
#pragma unroll
  for (int c = 0; c < 32; ++c) g2a[c] = g2s[rp][c];

#pragma unroll
  for (int c = 0; c < 16; ++c) {
    int e = h * 16 + c;
    float acc = b2[e];
#pragma unroll
    for (int k = 0; k < 32; ++k)
      acc = fmaf(g2a[k], w2[e * 32 + k], acc);     // uniform -> s_load
    spgP[e * PIX + g] = sigmoidf_(acc);
  }
}

// ---------------- fused forcing + temporal scan over T=24 (in place), emit h_out ----------
__global__ void __launch_bounds__(256) k_scan(
    float* __restrict__ u, const float* __restrict__ spgP,
    const float* __restrict__ gate, const float* __restrict__ srcr,
    const float* __restrict__ srci, const float* __restrict__ ofr_p,
    const float* __restrict__ ofi_p, const float* __restrict__ odr_p,
    const float* __restrict__ odi_p,
    const float* __restrict__ hre, const float* __restrict__ him,
    float* __restrict__ out) {
  int p = blockIdx.x * 256 + threadIdx.x;   // 0..4095
  int e = blockIdx.y;                        // 0..31 (block-uniform)
  int b = blockIdx.z;                        // 0..1
  float ur = 0.f, ui = 0.f;
  for (int t = 0; t < 24; ++t) {
    int n = b * 24 + t;
    int ie = n * 32 + e;
    int idx  = e * PIX + n * 4096 + p;
    int idxi = (32 + e) * PIX + n * 4096 + p;
    float gc = gate[ie] * spgP[idx];
    float xr = u[idx], xi = u[idxi];
    float om = 1.f - gc;
    float fr2 = xr * gc + srcr[ie] * om;
    float fi2 = xi * gc + srci[ie] * om;
    float ofr = ofr_p[ie], ofi = ofi_p[ie];
    float utr = fr2 * ofr - fi2 * ofi;
    float uti = fr2 * ofi + fi2 * ofr;
    if (t == 0) {
      int hb = (b * 4096 + p) * 32 + e;
      float hr = hre[hb], hi = him[hb];
      float odr0 = odr_p[ie], odi0 = odi_p[ie];
      utr += hr * odr0 - hi * odi0;
      uti += hr * odi0 + hi * odr0;
    }
    float ar = odr_p[ie], ai = odi_p[ie];
    float nr = ar * ur - ai * ui + utr;
    float ni = ar * ui + ai * ur + uti;
    ur = nr; ui = ni;
    u[idx] = ur;
    u[idxi] = ui;
  }
  out[HOUT_RE + (b * 4096 + p) * 32 + e] = ur;
  out[HOUT_IM + (b * 4096 + p) * 32 + e] = ui;
}

// ---------------- dec(Winv MFMA) + LN_t + FFN MFMA + z, weights from global --------------
// LDS: dnp[64][35] + ho[64][67] + ps = 28KB -> 5 blocks/CU. Strides 35/67 kill conflicts.
__global__ void __launch_bounds__(256) k_final(
    const float* __restrict__ u, float* __restrict__ out,
    const unsigned* __restrict__ wibP, const unsigned* __restrict__ w1bP,
    const unsigned* __restrict__ w2bP,
    const float* __restrict__ lg, const float* __restrict__ lb,
    const float* __restrict__ b1, const float* __restrict__ b2) {
  __shared__ unsigned dnp[64][35];
  __shared__ unsigned ho[64][67];
  __shared__ float ps1[64][5];
  __shared__ float ps2[64][5];

  int tid = threadIdx.x;
  int gbase = blockIdx.x * 256;
  int l = tid & 63, wv = tid >> 6;
  int l15 = l & 15, l4 = l >> 4;
  int p64 = l, q = wv;
  const uint4* wi4 = (const uint4*)wibP;   // [64][8]
  const uint4* w14 = (const uint4*)w1bP;   // [128][8]
  const uint4* w24 = (const uint4*)w2bP;   // [64][16]

  float bb1v[8], bb2v[4];
#pragma unroll
  for (int Hn = 0; Hn < 8; ++Hn) bb1v[Hn] = b1[Hn * 16 + l15];
#pragma unroll
  for (int On = 0; On < 4; ++On) bb2v[On] = b2[On * 16 + l15];

  for (int ph = 0; ph < 4; ++ph) {
    int gg = gbase + ph * 64 + p64;
    int arow = wv * 16 + l15;

    float uv[16];
#pragma unroll
    for (int i = 0; i < 16; ++i) uv[i] = u[(q * 16 + i) * PIX + gg];
#pragma unroll
    for (int ii = 0; ii < 8; ++ii)
      dnp[p64][q * 8 + ii] = pk2(uv[2 * ii], uv[2 * ii + 1]);
    __syncthreads();   // A

    {
      FU a0, a1;
#pragma unroll
      for (int jj = 0; jj < 4; ++jj) {
        a0.u[jj] = dnp[arow][l4 * 4 + jj];
        a1.u[jj] = dnp[arow][16 + l4 * 4 + jj];
      }
      float (*decf)[67] = (float(*)[67])ho;
#pragma unroll
      for (int Nt = 0; Nt < 4; ++Nt) {
        f32x4 acc = (f32x4){0.f, 0.f, 0.f, 0.f};
        FU4 b0f, b1f;
        int brow = Nt * 16 + l15;
        b0f.v = wi4[brow * 8 + l4];
        b1f.v = wi4[brow * 8 + 4 + l4];
        acc = __builtin_amdgcn_mfma_f32_16x16x32_bf16(a0.f, b0f.f, acc, 0, 0, 0);
        acc = __builtin_amdgcn_mfma_f32_16x16x32_bf16(a1.f, b1f.f, acc, 0, 0, 0);
#pragma unroll
        for (int r = 0; r < 4; ++r)
          decf[wv * 16 + l4 * 4 + r][Nt * 16 + l15] = acc[r];
      }
    }
    __syncthreads();   // B

    float dv[16];
    float s1 = 0.f, s2 = 0.f;
    {
      float (*decf)[67] = (float(*)[67])ho;
#pragma unroll
      for (int i = 0; i < 16; ++i) {
        dv[i] = decf[p64][q * 16 + i];
        s1 += dv[i];
        s2 += dv[i] * dv[i];
      }
    }
    ps1[p64][q] = s1;
    ps2[p64][q] = s2;
    __syncthreads();   // C
    float m  = (ps1[p64][0] + ps1[p64][1] + ps1[p64][2] + ps1[p64][3]) * (1.f / 64.f);
    float e2 = (ps2[p64][0] + ps2[p64][1] + ps2[p64][2] + ps2[p64][3]) * (1.f / 64.f);
    float rs = rsqrtf(e2 - m * m + 1e-5f);
#pragma unroll
    for (int ii = 0; ii < 8; ++ii) {
      int c0 = q * 16 + 2 * ii;
      float a = (dv[2 * ii]     - m) * rs * lg[c0]     + lb[c0];
      float bvl = (dv[2 * ii + 1] - m) * rs * lg[c0 + 1] + lb[c0 + 1];
      dnp[p64][q * 8 + ii] = pk2(a, bvl);
    }
    __syncthreads();   // D

    FU a0, a1;
#pragma unroll
    for (int jj = 0; jj < 4; ++jj) {
      a0.u[jj] = dnp[arow][l4 * 4 + jj];
      a1.u[jj] = dnp[arow][16 + l4 * 4 + jj];
    }
    f32x4 acc[8];
#pragma unroll
    for (int Hn = 0; Hn < 8; ++Hn) {
      float bb = bb1v[Hn];
      acc[Hn] = (f32x4){bb, bb, bb, bb};
      FU4 b0f, b1f;
      int brow = Hn * 16 + l15;
      b0f.v = w14[brow * 8 + l4];
      b1f.v = w14[brow * 8 + 4 + l4];
      acc[Hn] = __builtin_amdgcn_mfma_f32_16x16x32_bf16(a0.f, b0f.f, acc[Hn], 0, 0, 0);
      acc[Hn] = __builtin_amdgcn_mfma_f32_16x16x32_bf16(a1.f, b1f.f, acc[Hn], 0, 0, 0);
    }
    unsigned short (*hidb)[134] = (unsigned short(*)[134])ho;
#pragma unroll
    for (int Hn = 0; Hn < 8; ++Hn) {
#pragma unroll
      for (int r = 0; r < 4; ++r) {
        float v = acc[Hn][r];
        v = v * sigmoidf_(v);
        hidb[wv * 16 + l4 * 4 + r][Hn * 16 + l15] = f2bf(v);
      }
    }
    __syncthreads();   // E: TBAA fence (ushort stores -> u32 loads)

    FU a2[4];
#pragma unroll
    for (int kk = 0; kk < 4; ++kk)
#pragma unroll
      for (int jj = 0; jj < 4; ++jj)
        a2[kk].u[jj] = ((unsigned(*)[67])ho)[arow][kk * 16 + l4 * 4 + jj];
    f32x4 acc2[4];
#pragma unroll
    for (int On = 0; On < 4; ++On) {
      float bb = bb2v[On];
      acc2[On] = (f32x4){bb, bb, bb, bb};
#pragma unroll
      for (int kk = 0; kk < 4; ++kk) {
        FU4 b2f;
        b2f.v = w24[(On * 16 + l15) * 16 + kk * 4 + l4];
        acc2[On] = __builtin_amdgcn_mfma_f32_16x16x32_bf16(a2[kk].f, b2f.f, acc2[On], 0, 0, 0);
      }
    }
    float (*o2f)[67] = (float(*)[67])ho;
#pragma unroll
    for (int On = 0; On < 4; ++On)
#pragma unroll
      for (int r = 0; r < 4; ++r)
        o2f[wv * 16 + l4 * 4 + r][On * 16 + l15] = acc2[On][r];
    __syncthreads();   // F

    {
      int nn = gg >> 12, pim = gg & 4095;
#pragma unroll
      for (int i = 0; i < 16; ++i) {
        int c = q * 16 + i;
        float val = o2f[p64][c] + dv[i];
        int d = c & 31;
        long off = ((c < 32) ? (long)MAIN_RE : (long)MAIN_IM) + (long)(nn * 32 + d) * 4096 + pim;
        out[off] += val;
      }
    }
    __syncthreads();   // G: protect ho (o2f) reads vs next-phase dnp/decf writes
  }
}

extern "C" void kernel_launch(void* const* d_in, const int* in_sizes, int n_in,
                              void* d_out, int out_size, void* d_ws, size_t ws_size,
                              hipStream_t stream) {
  (void)in_sizes; (void)n_in; (void)out_size; (void)ws_size;
  const float* xre      = (const float*)d_in[0];
  const float* xim      = (const float*)d_in[1];
  const float* hre      = (const float*)d_in[2];
  const float* him      = (const float*)d_in[3];
  const float* flux_re  = (const float*)d_in[4];
  const float* flux_im  = (const float*)d_in[5];
  const float* dt_seq   = (const float*)d_in[6];
  const float* ln_s_g   = (const float*)d_in[7];
  const float* ln_s_b   = (const float*)d_in[8];
  const float* conv_w   = (const float*)d_in[9];
  const float* conv_b   = (const float*)d_in[10];
  const float* ln_t_g   = (const float*)d_in[11];
  const float* ln_t_b   = (const float*)d_in[12];
  const float* W_re     = (const float*)d_in[13];
  const float* W_im     = (const float*)d_in[14];
  const float* lam_flux = (const float*)d_in[15];
  const float* bf_re    = (const float*)d_in[16];
  const float* bf_im    = (const float*)d_in[17];
  const float* c_re     = (const float*)d_in[18];
  const float* c_im     = (const float*)d_in[19];
  const float* g_w      = (const float*)d_in[20];
  const float* g_b      = (const float*)d_in[21];
  const float* a_decay  = (const float*)d_in[22];
  const float* b_freq   = (const float*)d_in[23];
  const float* ffn_w1   = (const float*)d_in[24];
  const float* ffn_b1   = (const float*)d_in[25];
  const float* ffn_w2   = (const float*)d_in[26];
  const float* ffn_b2   = (const float*)d_in[27];
  const float* sg_w1    = (const float*)d_in[28];
  const float* sg_b1    = (const float*)d_in[29];
  const float* sg_dw    = (const float*)d_in[30];
  const float* sg_w2    = (const float*)d_in[31];
  const float* sg_b2    = (const float*)d_in[32];
  float* out = (float*)d_out;
  float* ws  = (float*)d_ws;

  k_invert<<<1, 256, 0, stream>>>(W_re, W_im, ws);
  k_wprep<<<144, 256, 0, stream>>>(conv_w, (unsigned short*)(ws + WS_WPK));
  k_eprep<<<8, 256, 0, stream>>>(W_re, W_im, sg_w1,
                                 (unsigned*)(ws + WS_WE), (unsigned*)(ws + WS_SG));
  k_fprep<<<16, 256, 0, stream>>>(ffn_w1, ffn_w2,
                                  (unsigned*)(ws + WS_W1B), (unsigned*)(ws + WS_W2B));
  k_ln_s<<<PIX / 256, 256, 0, stream>>>(xre, xim, ln_s_g, ln_s_b, ws);
  k_conv<<<768, 256, 0, stream>>>((const unsigned*)(ws + WS_XN),
                                  (const unsigned short*)(ws + WS_WPK),
                                  conv_b, xre, xim, out);
  k_xeig<<<768, 256, 0, stream>>>(out, (const unsigned*)(ws + WS_WE),
                                  (const unsigned*)(ws + WS_SG),
                                  ws + WS_XE, ws + WS_G1, sg_b1, ws + WS_PART);
  k_flux<<<1, 64, 0, stream>>>(ws, out, dt_seq, flux_re, flux_im, lam_flux,
                               bf_re, bf_im, c_re, c_im, g_w, g_b, a_decay, b_freq);
  k_gate<<<PIX / 128, 256, 0, stream>>>(ws + WS_G1, ws + WS_G2, sg_dw, sg_w2, sg_b2);
  k_scan<<<dim3(4096 / 256, 32, 2), 256, 0, stream>>>(ws + WS_XE, ws + WS_G2,
                                                      ws + WS_GATE, ws + WS_SRCR, ws + WS_SRCI,
                                                      ws + WS_OFR, ws + WS_OFI,
                                                      ws + WS_ODR, ws + WS_ODI,
                                                      hre, him, out);
  k_final<<<768, 256, 0, stream>>>(ws + WS_XE, out,
                                   (const unsigned*)(ws + WS_WIB),
                                   (const unsigned*)(ws + WS_W1B),
                                   (const unsigned*)(ws + WS_W2B),
                                   ln_t_g, ln_t_b, ffn_b1, ffn_b2);
}

// Round 15
// 324.195 us; speedup vs baseline: 1.1513x; 1.1513x over previous
//
#include <hip/hip_runtime.h>
#include <math.h>

#define BB 2
#define TT 24
#define DD 32
#define HWp 4096            // 64*64
#define NN (BB*TT)          // 48
#define PIX (NN*HWp)        // 196608
#define C2 (2*DD)           // 64

// d_out offsets (floats)
#define MAIN_RE 0
#define MAIN_IM (NN*DD*HWp)              // 6291456
#define HOUT_RE (2*NN*DD*HWp)            // 12582912
#define HOUT_IM (HOUT_RE + BB*HWp*DD)    // 12845056
#define FLUX_RE (HOUT_RE + 2*BB*HWp*DD)  // 13107200
#define FLUX_IM (FLUX_RE + BB*DD)        // 13107264

// ws offsets (floats)
#define WS_XN   0                        // PIX*64 (bf16 xn for conv)
#define WS_XE   (WS_XN + PIX*C2)         // PIX*64  xe -> u planes
#define WS_G1   (WS_XE + PIX*C2)         // PIX*32  g1 planes
#define WS_G2   (WS_G1 + PIX*DD)         // PIX*32  spg planes
#define WS_WINV (WS_G2 + PIX*DD)         // 2048 f32
#define WS_SUMS (WS_WINV + 2048)         // 3072 (unused)
#define WS_GATE (WS_SUMS + 3072)         // 1536
#define WS_SRCR (WS_GATE + 1536)
#define WS_SRCI (WS_SRCR + 1536)
#define WS_ODR  (WS_SRCI + 1536)
#define WS_ODI  (WS_ODR + 1536)
#define WS_OFR  (WS_ODI + 1536)
#define WS_OFI  (WS_OFR + 1536)
#define WS_WPK  (WS_OFI + 1536)          // 36864 ushorts = 18432 floats
#define WS_PART (WS_WPK + 18432)         // 48*16*64 floats
#define WS_WE   (WS_PART + 49152)        // 2048 u32 eig weights [64][32]
#define WS_SG   (WS_WE + 2048)           // 1024 u32 sg1 weights [32][32]
#define WS_WIB  (WS_SG + 1024)           // 2048 u32 Winv packed [64][32]

typedef __attribute__((ext_vector_type(8))) short bf16x8;
typedef __attribute__((ext_vector_type(4))) float f32x4;
union FU { unsigned u[4]; bf16x8 f; };
union FU4 { uint4 v; unsigned u[4]; bf16x8 f; };

__device__ __forceinline__ float sigmoidf_(float x) { return 1.f / (1.f + expf(-x)); }
__device__ __forceinline__ float softplusf_(float x) { return log1pf(expf(x)); }
__device__ __forceinline__ unsigned short f2bf(float f) {
  unsigned u = __float_as_uint(f);
  return (unsigned short)((u + 0x7FFFu + ((u >> 16) & 1u)) >> 16);   // RNE
}
__device__ __forceinline__ unsigned pk2(float lo, float hi) {
  return (unsigned)f2bf(lo) | ((unsigned)f2bf(hi) << 16);
}

// ---------------- Gauss-Jordan inverse of Wb (32x32 complex) + bf16 B-frag pack ----------
__global__ void k_invert(const float* __restrict__ Wre, const float* __restrict__ Wim,
                         float* __restrict__ ws) {
  __shared__ float Mre[32][64];
  __shared__ float Mim[32][64];
  __shared__ float fre[32], fim[32];
  __shared__ float pr_s, pi_s;
  __shared__ int piv_s;
  int tid = threadIdx.x;  // 256 threads
  for (int idx = tid; idx < 2048; idx += 256) {
    int i = idx >> 6, j = idx & 63;
    if (j < 32) { Mre[i][j] = Wre[i * 32 + j]; Mim[i][j] = Wim[i * 32 + j]; }
    else        { Mre[i][j] = (j - 32 == i) ? 1.f : 0.f; Mim[i][j] = 0.f; }
  }
  __syncthreads();
  for (int k = 0; k < 32; ++k) {
    if (tid == 0) {
      int best = k; float bm = fabsf(Mre[k][k]) + fabsf(Mim[k][k]);
      for (int r = k + 1; r < 32; ++r) {
        float m = fabsf(Mre[r][k]) + fabsf(Mim[r][k]);
        if (m > bm) { bm = m; best = r; }
      }
      piv_s = best;
    }
    __syncthreads();
    int pv = piv_s;
    if (pv != k && tid < 64) {
      float tr = Mre[k][tid], ti = Mim[k][tid];
      Mre[k][tid] = Mre[pv][tid]; Mim[k][tid] = Mim[pv][tid];
      Mre[pv][tid] = tr; Mim[pv][tid] = ti;
    }
    __syncthreads();
    if (tid == 0) {
      float a = Mre[k][k], b = Mim[k][k];
      float d = a * a + b * b;
      pr_s = a / d; pi_s = -b / d;
    }
    __syncthreads();
    float pr = pr_s, pi = pi_s;
    if (tid < 64) {
      float a = Mre[k][tid], b = Mim[k][tid];
      Mre[k][tid] = a * pr - b * pi;
      Mim[k][tid] = a * pi + b * pr;
    }
    __syncthreads();
    if (tid < 32) { fre[tid] = Mre[tid][k]; fim[tid] = Mim[tid][k]; }
    __syncthreads();
    for (int idx = tid; idx < 2048; idx += 256) {
      int i = idx >> 6, j = idx & 63;
      if (i != k) {
        float fr = fre[i], fi = fim[i];
        float ar = Mre[k][j], ai = Mim[k][j];
        Mre[i][j] -= fr * ar - fi * ai;
        Mim[i][j] -= fr * ai + fi * ar;
      }
    }
    __syncthreads();
  }
  for (int idx = tid; idx < 1024; idx += 256) {
    int e = idx >> 5, d = idx & 31;
    ws[WS_WINV + e * 32 + d] = Mre[e][32 + d];
    ws[WS_WINV + 1024 + e * 32 + d] = Mim[e][32 + d];
  }
  unsigned* wib = (unsigned*)(ws + WS_WIB);
  for (int idx = tid; idx < 2048; idx += 256) {
    int j = idx >> 5, kp = idx & 31;
    float v[2];
#pragma unroll
    for (int h = 0; h < 2; ++h) {
      int k = 2 * kp + h;
      float x;
      if (j < 32) x = (k < 32) ? Mre[k][32 + j] : -Mim[k - 32][32 + j];
      else        x = (k < 32) ? Mim[k][32 + (j - 32)] : Mre[k - 32][32 + (j - 32)];
      v[h] = x;
    }
    wib[idx] = pk2(v[0], v[1]);
  }
}

// ---------------- weight pre-pack: wpack[tap][oc][ci] bf16 <- conv_w[oc][ci][tap] f32 ----
__global__ void k_wprep(const float* __restrict__ w, unsigned short* __restrict__ wpk) {
  int idx = blockIdx.x * 256 + threadIdx.x;
  if (idx >= 9 * 64 * 64) return;
  int tap = idx >> 12;
  int rem = idx & 4095;
  int oc = rem >> 6, ci = rem & 63;
  wpk[idx] = f2bf(w[(oc * 64 + ci) * 9 + tap]);
}

// ---------------- eig + sg1 weight pre-pack (bf16 [N][Kpair] B-fragment layout) ----------
__global__ void k_eprep(const float* __restrict__ Wre, const float* __restrict__ Wim,
                        const float* __restrict__ sgw1,
                        unsigned* __restrict__ we, unsigned* __restrict__ sg) {
  int idx = blockIdx.x * 256 + threadIdx.x;
  if (idx < 2048) {
    int j = idx >> 5, kp = idx & 31;
    float v[2];
#pragma unroll
    for (int h = 0; h < 2; ++h) {
      int k = 2 * kp + h;
      float x;
      if (j < 32) x = (k < 32) ? Wre[k * 32 + j] : -Wim[(k - 32) * 32 + j];
      else        x = (k < 32) ? Wim[k * 32 + (j - 32)] : Wre[(k - 32) * 32 + (j - 32)];
      v[h] = x;
    }
    we[idx] = pk2(v[0], v[1]);
  }
  if (idx < 1024) {
    int oc = idx >> 5, kp = idx & 31;
    sg[idx] = pk2(sgw1[oc * 64 + 2 * kp], sgw1[oc * 64 + 2 * kp + 1]);
  }
}

// ---------------- spatial LayerNorm -> xn bf16 channels-last [n][pix][64] ----------------
__global__ void k_ln_s(const float* __restrict__ xre, const float* __restrict__ xim,
                       const float* __restrict__ g, const float* __restrict__ b,
                       float* __restrict__ ws) {
  int gid = blockIdx.x * 256 + threadIdx.x;
  if (gid >= PIX) return;
  int n = gid >> 12, p = gid & 4095;
  float v[64];
  float s = 0.f;
#pragma unroll
  for (int c = 0; c < 32; ++c) { v[c] = xre[(n * 32 + c) * 4096 + p]; s += v[c]; }
#pragma unroll
  for (int c = 0; c < 32; ++c) { v[32 + c] = xim[(n * 32 + c) * 4096 + p]; s += v[32 + c]; }
  float m = s * (1.f / 64.f);
  float vs = 0.f;
#pragma unroll
  for (int c = 0; c < 64; ++c) { float d = v[c] - m; vs += d * d; }
  float rs = rsqrtf(vs * (1.f / 64.f) + 1e-5f);
#pragma unroll
  for (int c = 0; c < 64; ++c) v[c] = (v[c] - m) * rs * g[c] + b[c];
  uint4* dst = (uint4*)ws + gid * 8;
#pragma unroll
  for (int q = 0; q < 8; ++q) {
    uint4 u;
    u.x = pk2(v[q * 8 + 0], v[q * 8 + 1]);
    u.y = pk2(v[q * 8 + 2], v[q * 8 + 3]);
    u.z = pk2(v[q * 8 + 4], v[q * 8 + 5]);
    u.w = pk2(v[q * 8 + 6], v[q * 8 + 7]);
    dst[q] = u;
  }
}

// ---------------- 3x3 conv 64->64 as 9 shifted bf16 MFMA GEMMs ----------------
__global__ void __launch_bounds__(256) k_conv(
    const unsigned* __restrict__ xnb_u, const unsigned short* __restrict__ wpk,
    const float* __restrict__ bconv,
    const float* __restrict__ xre, const float* __restrict__ xim,
    float* __restrict__ out) {
  __shared__ unsigned xls[6 * 66 * 36];
  int bid = blockIdx.x;
  int n = bid >> 4;
  int y0 = (bid & 15) * 4;
  int tid = threadIdx.x;
  int wv = tid >> 6, l = tid & 63;
  int l15 = l & 15, l4 = l >> 4;

  const uint4* xnb4 = (const uint4*)xnb_u;
  for (int idx = tid; idx < 396; idx += 256) {
    int r = idx / 66, c = idx - r * 66;
    int y = y0 - 1 + r, x = c - 1;
    bool valid = ((unsigned)y < 64u) & ((unsigned)x < 64u);
    int pg = n * 4096 + y * 64 + x;
    uint4 z; z.x = z.y = z.z = z.w = 0u;
#pragma unroll
    for (int q = 0; q < 8; ++q) {
      uint4 v = valid ? xnb4[pg * 8 + q] : z;
      *(uint4*)&xls[idx * 36 + q * 4] = v;
    }
  }
  __syncthreads();

  f32x4 acc[4][4];
#pragma unroll
  for (int Nt = 0; Nt < 4; ++Nt) {
    float bb = bconv[Nt * 16 + l15];
#pragma unroll
    for (int mt = 0; mt < 4; ++mt) acc[mt][Nt] = (f32x4){bb, bb, bb, bb};
  }

  const uint4* wq = (const uint4*)wpk;
#pragma unroll
  for (int tap = 0; tap < 9; ++tap) {
    int ky = tap / 3, kx = tap - ky * 3;
    int rowbase = (wv + ky) * 66 + kx + l15;
#pragma unroll
    for (int ks = 0; ks < 2; ++ks) {
      FU4 B[4];
#pragma unroll
      for (int Nt = 0; Nt < 4; ++Nt)
        B[Nt].v = wq[tap * 512 + (Nt * 16 + l15) * 8 + ks * 4 + l4];
#pragma unroll
      for (int mt = 0; mt < 4; ++mt) {
        FU4 A;
        A.v = *(const uint4*)&xls[(rowbase + mt * 16) * 36 + ks * 16 + l4 * 4];
#pragma unroll
        for (int Nt = 0; Nt < 4; ++Nt)
          acc[mt][Nt] = __builtin_amdgcn_mfma_f32_16x16x32_bf16(A.f, B[Nt].f, acc[mt][Nt], 0, 0, 0);
      }
    }
  }

#pragma unroll
  for (int Nt = 0; Nt < 4; ++Nt) {
    int oc = Nt * 16 + l15;
    int d = oc & 31;
    const float* resid = (oc < 32) ? xre : xim;
    float* dst = out + ((oc < 32) ? MAIN_RE : MAIN_IM) + (n * 32 + d) * 4096;
    const float* rsd = resid + (n * 32 + d) * 4096;
#pragma unroll
    for (int mt = 0; mt < 4; ++mt) {
      int pixbase = (y0 + wv) * 64 + mt * 16 + l4 * 4;
#pragma unroll
      for (int r = 0; r < 4; ++r)
        dst[pixbase + r] = rsd[pixbase + r] + acc[mt][Nt][r];
    }
  }
}

// ---------------- x_eig v4: MFMA dual-GEMM, LDS weights, stride-35/67, x-prefetch ----------
__global__ void __launch_bounds__(256) k_xeig(
    const float* __restrict__ out, const unsigned* __restrict__ weP,
    const unsigned* __restrict__ sgP, float* __restrict__ xe,
    float* __restrict__ g1, const float* __restrict__ sgb1,
    float* __restrict__ part) {
  __shared__ unsigned WeT[64][35];
  __shared__ unsigned SgT[32][35];
  __shared__ unsigned xp[64][35];
  __shared__ float xef[64][67];

  int tid = threadIdx.x;
  int gbase = blockIdx.x * 256;
  int l = tid & 63, wv = tid >> 6;
  int l15 = l & 15, l4 = l >> 4;
  int p64 = l, q = wv;

  {
#pragma unroll
    for (int i = 0; i < 8; ++i) {
      int idx = tid + i * 256;
      WeT[idx >> 5][idx & 31] = weP[idx];
    }
#pragma unroll
    for (int i = 0; i < 4; ++i) {
      int idx = tid + i * 256;
      SgT[idx >> 5][idx & 31] = sgP[idx];
    }
  }
  float ssum[16];
#pragma unroll
  for (int i = 0; i < 16; ++i) ssum[i] = 0.f;

  // prefetch phase-0 x
  float xv[16];
  {
    int gg = gbase + p64;
    int n = gg >> 12, p = gg & 4095;
#pragma unroll
    for (int i = 0; i < 16; ++i) {
      int c = q * 16 + i;
      xv[i] = (c < 32) ? out[MAIN_RE + (n * 32 + c) * 4096 + p]
                       : out[MAIN_IM + (n * 32 + (c - 32)) * 4096 + p];
    }
  }
  __syncthreads();

  for (int ph = 0; ph < 4; ++ph) {
    int gg = gbase + ph * 64 + p64;

#pragma unroll
    for (int ii = 0; ii < 8; ++ii)
      xp[p64][q * 8 + ii] = pk2(xv[2 * ii], xv[2 * ii + 1]);
    // prefetch next phase's x (overlaps with this phase's compute)
    if (ph < 3) {
      int gg2 = gg + 64;
      int n2 = gg2 >> 12, p2 = gg2 & 4095;
#pragma unroll
      for (int i = 0; i < 16; ++i) {
        int c = q * 16 + i;
        xv[i] = (c < 32) ? out[MAIN_RE + (n2 * 32 + c) * 4096 + p2]
                         : out[MAIN_IM + (n2 * 32 + (c - 32)) * 4096 + p2];
      }
    }
    __syncthreads();   // A

    int arow = wv * 16 + l15;
    FU a0, a1;
#pragma unroll
    for (int jj = 0; jj < 4; ++jj) {
      a0.u[jj] = xp[arow][l4 * 4 + jj];
      a1.u[jj] = xp[arow][16 + l4 * 4 + jj];
    }
#pragma unroll
    for (int Nt = 0; Nt < 4; ++Nt) {
      f32x4 acc = (f32x4){0.f, 0.f, 0.f, 0.f};
      FU b0f, b1f;
      int brow = Nt * 16 + l15;
#pragma unroll
      for (int jj = 0; jj < 4; ++jj) {
        b0f.u[jj] = WeT[brow][l4 * 4 + jj];
        b1f.u[jj] = WeT[brow][16 + l4 * 4 + jj];
      }
      acc = __builtin_amdgcn_mfma_f32_16x16x32_bf16(a0.f, b0f.f, acc, 0, 0, 0);
      acc = __builtin_amdgcn_mfma_f32_16x16x32_bf16(a1.f, b1f.f, acc, 0, 0, 0);
#pragma unroll
      for (int r = 0; r < 4; ++r)
        xef[wv * 16 + l4 * 4 + r][Nt * 16 + l15] = acc[r];
    }
    __syncthreads();   // B

    float xo[16];
#pragma unroll
    for (int i = 0; i < 16; ++i) {
      xo[i] = xef[p64][q * 16 + i];
      ssum[i] += xo[i];
      xe[(q * 16 + i) * PIX + gg] = xo[i];
    }
#pragma unroll
    for (int ii = 0; ii < 8; ++ii)
      xp[p64][q * 8 + ii] = pk2(xo[2 * ii], xo[2 * ii + 1]);
    __syncthreads();   // C

    FU c0, c1;
#pragma unroll
    for (int jj = 0; jj < 4; ++jj) {
      c0.u[jj] = xp[arow][l4 * 4 + jj];
      c1.u[jj] = xp[arow][16 + l4 * 4 + jj];
    }
#pragma unroll
    for (int Nt = 0; Nt < 2; ++Nt) {
      float bb = sgb1[Nt * 16 + l15];
      f32x4 acc = (f32x4){bb, bb, bb, bb};
      FU b0f, b1f;
      int brow = Nt * 16 + l15;
#pragma unroll
      for (int jj = 0; jj < 4; ++jj) {
        b0f.u[jj] = SgT[brow][l4 * 4 + jj];
        b1f.u[jj] = SgT[brow][16 + l4 * 4 + jj];
      }
      acc = __builtin_amdgcn_mfma_f32_16x16x32_bf16(c0.f, b0f.f, acc, 0, 0, 0);
      acc = __builtin_amdgcn_mfma_f32_16x16x32_bf16(c1.f, b1f.f, acc, 0, 0, 0);
#pragma unroll
      for (int r = 0; r < 4; ++r) {
        float v = acc[r];
        xef[wv * 16 + l4 * 4 + r][Nt * 16 + l15] = v * sigmoidf_(v);
      }
    }
    __syncthreads();   // D

#pragma unroll
    for (int i = 0; i < 8; ++i)
      g1[(q * 8 + i) * PIX + gg] = xef[p64][q * 8 + i];
    __syncthreads();   // E: protect xp/xef reuse next phase
  }

#pragma unroll
  for (int i = 0; i < 16; ++i) {
    float v = ssum[i];
    v += __shfl_xor(v, 1);
    v += __shfl_xor(v, 2);
    v += __shfl_xor(v, 4);
    v += __shfl_xor(v, 8);
    v += __shfl_xor(v, 16);
    v += __shfl_xor(v, 32);
    if (l == 0) part[blockIdx.x * 64 + q * 16 + i] = v;
  }
}

// ---------------- flux scan (T=24) + all per-(b,t,d) coefficients ----------------
__global__ void k_flux(float* __restrict__ ws, float* __restrict__ out,
                       const float* __restrict__ dt_seq,
                       const float* __restrict__ flux_re, const float* __restrict__ flux_im,
                       const float* __restrict__ lam_flux,
                       const float* __restrict__ bf_re, const float* __restrict__ bf_im,
                       const float* __restrict__ c_re, const float* __restrict__ c_im,
                       const float* __restrict__ g_w, const float* __restrict__ g_b,
                       const float* __restrict__ a_decay, const float* __restrict__ b_freq) {
  int tid = threadIdx.x;
  if (tid >= 64) return;
  int b = tid >> 5, e = tid & 31;
  float sp_lf = softplusf_(lam_flux[e]);
  float lr = -softplusf_(a_decay[e]);
  float li = b_freq[e];
  float den = lr * lr + li * li;
  float bfr = bf_re[e], bfi = bf_im[e];
  float cr = c_re[e], ci = c_im[e];
  float fr = flux_re[b * 32 + e], fi = flux_im[b * 32 + e];
  const float* part = ws + WS_PART;
  for (int t = 0; t < 24; ++t) {
    int n = b * 24 + t;
    float dt = dt_seq[n];
    float A = expf(-sp_lf * dt);
    float xmr = 0.f, xmi = 0.f;
#pragma unroll
    for (int j = 0; j < 16; ++j) {
      xmr += part[(n * 16 + j) * 64 + e];
      xmi += part[(n * 16 + j) * 64 + 32 + e];
    }
    xmr *= (1.f / 4096.f);
    xmi *= (1.f / 4096.f);
    float Xr = (bfr * xmr - bfi * xmi) * dt;
    float Xi = (bfr * xmi + bfi * xmr) * dt;
    fr = A * fr + Xr;
    fi = A * fi + Xi;
    ws[WS_GATE + n * 32 + e] = sigmoidf_(fr * g_w[e] + g_b[e]);
    ws[WS_SRCR + n * 32 + e] = fr * cr - fi * ci;
    ws[WS_SRCI + n * 32 + e] = fr * ci + fi * cr;
    float er = expf(lr * dt);
    float odr = er * cosf(li * dt);
    float odi = er * sinf(li * dt);
    ws[WS_ODR + n * 32 + e] = odr;
    ws[WS_ODI + n * 32 + e] = odi;
    float nr = odr - 1.f, ni = odi;
    ws[WS_OFR + n * 32 + e] = (nr * lr + ni * li) / den;
    ws[WS_OFI + n * 32 + e] = (ni * lr - nr * li) / den;
  }
  out[FLUX_RE + b * 32 + e] = fr;
  out[FLUX_IM + b * 32 + e] = fi;
}

// ---------------- gate v3: dw 3x3 (shuffle stencil) + sg3 + sigmoid -> spg planes ---------
__global__ void __launch_bounds__(256) k_gate(
    const float* __restrict__ g1, float* __restrict__ spgP,
    const float* __restrict__ dw, const float* __restrict__ w2,
    const float* __restrict__ b2) {
  __shared__ float g2s[128][33];
  int tid = threadIdx.x;
  int l = tid & 63;
  int wv = tid >> 6;
  int r = wv >> 1, h = wv & 1;
  int pixbase = blockIdx.x * 128;
  int n = pixbase >> 12;
  int y = ((pixbase & 4095) >> 6) + r;
  int g = pixbase + r * 64 + l;
  int rp = r * 64 + l;

#pragma unroll
  for (int c = 0; c < 16; ++c) {
    int oc = h * 16 + c;
    const float* src = g1 + oc * PIX + n * 4096;
    const float* w = dw + oc * 9;        // uniform -> s_load
    float r0 = (y > 0)  ? src[(y - 1) * 64 + l] : 0.f;
    float r1 = src[y * 64 + l];
    float r2 = (y < 63) ? src[(y + 1) * 64 + l] : 0.f;
    float l0 = __shfl_up(r0, 1), t0 = __shfl_down(r0, 1);
    float l1 = __shfl_up(r1, 1), t1 = __shfl_down(r1, 1);
    float l2 = __shfl_up(r2, 1), t2 = __shfl_down(r2, 1);
    if (l == 0)  { l0 = 0.f; l1 = 0.f; l2 = 0.f; }
    if (l == 63) { t0 = 0.f; t1 = 0.f; t2 = 0.f; }
    float acc = 0.f;
    acc = fmaf(l0, w[0], acc); acc = fmaf(r0, w[1], acc); acc = fmaf(t0, w[2], acc);
    acc = fmaf(l1, w[3], acc); acc = fmaf(r1, w[4], acc); acc = fmaf(t1, w[5], acc);
    acc = fmaf(l2, w[6], acc); acc = fmaf(r2, w[7], acc); acc = fmaf(t2, w[8], acc);
    g2s[rp][oc] = acc;
  }
  __syncthreads();
  float g2a[32];
#pragma unroll
  for (int c = 0; c < 32; ++c) g2a[c] = g2s[rp][c];

#pragma unroll
  for (int c = 0; c < 16; ++c) {
    int e = h * 16 + c;
    float acc = b2[e];
#pragma unroll
    for (int k = 0; k < 32; ++k)
      acc = fmaf(g2a[k], w2[e * 32 + k], acc);     // uniform -> s_load
    spgP[e * PIX + g] = sigmoidf_(acc);
  }
}

// ---------------- fused forcing + temporal scan over T=24 (in place), emit h_out ----------
__global__ void __launch_bounds__(256) k_scan(
    float* __restrict__ u, const float* __restrict__ spgP,
    const float* __restrict__ gate, const float* __restrict__ srcr,
    const float* __restrict__ srci, const float* __restrict__ ofr_p,
    const float* __restrict__ ofi_p, const float* __restrict__ odr_p,
    const float* __restrict__ odi_p,
    const float* __restrict__ hre, const float* __restrict__ him,
    float* __restrict__ out) {
  int p = blockIdx.x * 256 + threadIdx.x;   // 0..4095
  int e = blockIdx.y;                        // 0..31 (block-uniform)
  int b = blockIdx.z;                        // 0..1
  float ur = 0.f, ui = 0.f;
  for (int t = 0; t < 24; ++t) {
    int n = b * 24 + t;
    int ie = n * 32 + e;
    int idx  = e * PIX + n * 4096 + p;
    int idxi = (32 + e) * PIX + n * 4096 + p;
    float gc = gate[ie] * spgP[idx];
    float xr = u[idx], xi = u[idxi];
    float om = 1.f - gc;
    float fr2 = xr * gc + srcr[ie] * om;
    float fi2 = xi * gc + srci[ie] * om;
    float ofr = ofr_p[ie], ofi = ofi_p[ie];
    float utr = fr2 * ofr - fi2 * ofi;
    float uti = fr2 * ofi + fi2 * ofr;
    if (t == 0) {
      int hb = (b * 4096 + p) * 32 + e;
      float hr = hre[hb], hi = him[hb];
      float odr0 = odr_p[ie], odi0 = odi_p[ie];
      utr += hr * odr0 - hi * odi0;
      uti += hr * odi0 + hi * odr0;
    }
    float ar = odr_p[ie], ai = odi_p[ie];
    float nr = ar * ur - ai * ui + utr;
    float ni = ar * ui + ai * ur + uti;
    ur = nr; ui = ni;
    u[idx] = ur;
    u[idxi] = ui;
  }
  out[HOUT_RE + (b * 4096 + p) * 32 + e] = ur;
  out[HOUT_IM + (b * 4096 + p) * 32 + e] = ui;
}

// ---------------- dec(Winv MFMA) + LN_t + FFN MFMA + z, LDS weights, prefetch -------------
// Strides: dnp/wiT/w1T 35, ho/w2T 67 (bank-conflict-free). u+out prefetched per phase.
__global__ void __launch_bounds__(256) k_final(
    const float* __restrict__ u, float* __restrict__ out,
    const unsigned* __restrict__ wibP,
    const float* __restrict__ lg, const float* __restrict__ lb,
    const float* __restrict__ w1, const float* __restrict__ b1,
    const float* __restrict__ w2, const float* __restrict__ b2) {
  __shared__ unsigned wiT[64][35];
  __shared__ unsigned w1T[128][35];
  __shared__ unsigned w2T[64][67];
  __shared__ unsigned dnp[64][35];
  __shared__ unsigned ho[64][67];
  __shared__ float ps1[64][5];
  __shared__ float ps2[64][5];

  int tid = threadIdx.x;
  int gbase = blockIdx.x * 256;
  int l = tid & 63, wv = tid >> 6;
  int l15 = l & 15, l4 = l >> 4;
  int p64 = l, q = wv;

  {
#pragma unroll
    for (int i = 0; i < 8; ++i) {
      int idx = tid + i * 256;
      wiT[idx >> 5][idx & 31] = wibP[idx];
    }
    int hid = tid & 127, half = tid >> 7;
#pragma unroll
    for (int i = 0; i < 16; ++i) {
      int cp = half * 16 + i;
      w1T[hid][cp] = pk2(w1[(2 * cp) * 128 + hid], w1[(2 * cp + 1) * 128 + hid]);
    }
#pragma unroll
    for (int i = 0; i < 16; ++i) {
      int hp = wv * 16 + i;
      w2T[l][hp] = pk2(w2[(2 * hp) * 64 + l], w2[(2 * hp + 1) * 64 + l]);
    }
  }
  float bb1v[8], bb2v[4];
#pragma unroll
  for (int Hn = 0; Hn < 8; ++Hn) bb1v[Hn] = b1[Hn * 16 + l15];
#pragma unroll
  for (int On = 0; On < 4; ++On) bb2v[On] = b2[On * 16 + l15];

  // prefetch phase-0 u and out-RMW values
  float uv[16], ov[16];
  {
    int gg = gbase + p64;
    int nn = gg >> 12, pim = gg & 4095;
#pragma unroll
    for (int i = 0; i < 16; ++i) uv[i] = u[(q * 16 + i) * PIX + gg];
#pragma unroll
    for (int i = 0; i < 16; ++i) {
      int c = q * 16 + i;
      int d = c & 31;
      long off = ((c < 32) ? (long)MAIN_RE : (long)MAIN_IM) + (long)(nn * 32 + d) * 4096 + pim;
      ov[i] = out[off];
    }
  }
  __syncthreads();

  for (int ph = 0; ph < 4; ++ph) {
    int gg = gbase + ph * 64 + p64;
    int arow = wv * 16 + l15;

#pragma unroll
    for (int ii = 0; ii < 8; ++ii)
      dnp[p64][q * 8 + ii] = pk2(uv[2 * ii], uv[2 * ii + 1]);
    // prefetch next phase's u (overlaps the whole phase)
    if (ph < 3) {
      int gg2 = gg + 64;
#pragma unroll
      for (int i = 0; i < 16; ++i) uv[i] = u[(q * 16 + i) * PIX + gg2];
    }
    __syncthreads();   // A

    {
      FU a0, a1;
#pragma unroll
      for (int jj = 0; jj < 4; ++jj) {
        a0.u[jj] = dnp[arow][l4 * 4 + jj];
        a1.u[jj] = dnp[arow][16 + l4 * 4 + jj];
      }
      float (*decf)[67] = (float(*)[67])ho;
#pragma unroll
      for (int Nt = 0; Nt < 4; ++Nt) {
        f32x4 acc = (f32x4){0.f, 0.f, 0.f, 0.f};
        FU b0f, b1f;
        int brow = Nt * 16 + l15;
#pragma unroll
        for (int jj = 0; jj < 4; ++jj) {
          b0f.u[jj] = wiT[brow][l4 * 4 + jj];
          b1f.u[jj] = wiT[brow][16 + l4 * 4 + jj];
        }
        acc = __builtin_amdgcn_mfma_f32_16x16x32_bf16(a0.f, b0f.f, acc, 0, 0, 0);
        acc = __builtin_amdgcn_mfma_f32_16x16x32_bf16(a1.f, b1f.f, acc, 0, 0, 0);
#pragma unroll
        for (int r = 0; r < 4; ++r)
          decf[wv * 16 + l4 * 4 + r][Nt * 16 + l15] = acc[r];
      }
    }
    __syncthreads();   // B

    float dv[16];
    float s1 = 0.f, s2 = 0.f;
    {
      float (*decf)[67] = (float(*)[67])ho;
#pragma unroll
      for (int i = 0; i < 16; ++i) {
        dv[i] = decf[p64][q * 16 + i];
        s1 += dv[i];
        s2 += dv[i] * dv[i];
      }
    }
    ps1[p64][q] = s1;
    ps2[p64][q] = s2;
    __syncthreads();   // C
    float m  = (ps1[p64][0] + ps1[p64][1] + ps1[p64][2] + ps1[p64][3]) * (1.f / 64.f);
    float e2 = (ps2[p64][0] + ps2[p64][1] + ps2[p64][2] + ps2[p64][3]) * (1.f / 64.f);
    float rs = rsqrtf(e2 - m * m + 1e-5f);
#pragma unroll
    for (int ii = 0; ii < 8; ++ii) {
      int c0 = q * 16 + 2 * ii;
      float a = (dv[2 * ii]     - m) * rs * lg[c0]     + lb[c0];
      float bvl = (dv[2 * ii + 1] - m) * rs * lg[c0 + 1] + lb[c0 + 1];
      dnp[p64][q * 8 + ii] = pk2(a, bvl);
    }
    __syncthreads();   // D

    FU a0, a1;
#pragma unroll
    for (int jj = 0; jj < 4; ++jj) {
      a0.u[jj] = dnp[arow][l4 * 4 + jj];
      a1.u[jj] = dnp[arow][16 + l4 * 4 + jj];
    }
    f32x4 acc[8];
#pragma unroll
    for (int Hn = 0; Hn < 8; ++Hn) {
      float bb = bb1v[Hn];
      acc[Hn] = (f32x4){bb, bb, bb, bb};
      FU b0f, b1f;
      int brow = Hn * 16 + l15;
#pragma unroll
      for (int jj = 0; jj < 4; ++jj) {
        b0f.u[jj] = w1T[brow][l4 * 4 + jj];
        b1f.u[jj] = w1T[brow][16 + l4 * 4 + jj];
      }
      acc[Hn] = __builtin_amdgcn_mfma_f32_16x16x32_bf16(a0.f, b0f.f, acc[Hn], 0, 0, 0);
      acc[Hn] = __builtin_amdgcn_mfma_f32_16x16x32_bf16(a1.f, b1f.f, acc[Hn], 0, 0, 0);
    }
    unsigned short (*hidb)[134] = (unsigned short(*)[134])ho;
#pragma unroll
    for (int Hn = 0; Hn < 8; ++Hn) {
#pragma unroll
      for (int r = 0; r < 4; ++r) {
        float v = acc[Hn][r];
        v = v * sigmoidf_(v);
        hidb[wv * 16 + l4 * 4 + r][Hn * 16 + l15] = f2bf(v);
      }
    }
    __syncthreads();   // E: TBAA fence (ushort stores -> u32 loads)

    FU a2[4];
#pragma unroll
    for (int kk = 0; kk < 4; ++kk)
#pragma unroll
      for (int jj = 0; jj < 4; ++jj)
        a2[kk].u[jj] = ((unsigned(*)[67])ho)[arow][kk * 16 + l4 * 4 + jj];
    f32x4 acc2[4];
#pragma unroll
    for (int On = 0; On < 4; ++On) {
      float bb = bb2v[On];
      acc2[On] = (f32x4){bb, bb, bb, bb};
#pragma unroll
      for (int kk = 0; kk < 4; ++kk) {
        FU b2f;
#pragma unroll
        for (int jj = 0; jj < 4; ++jj)
          b2f.u[jj] = w2T[On * 16 + l15][kk * 16 + l4 * 4 + jj];
        acc2[On] = __builtin_amdgcn_mfma_f32_16x16x32_bf16(a2[kk].f, b2f.f, acc2[On], 0, 0, 0);
      }
    }
    float (*o2f)[67] = (float(*)[67])ho;
#pragma unroll
    for (int On = 0; On < 4; ++On)
#pragma unroll
      for (int r = 0; r < 4; ++r)
        o2f[wv * 16 + l4 * 4 + r][On * 16 + l15] = acc2[On][r];
    __syncthreads();   // F

    // ---- epilogue: pure stores (out values prefetched in ov) ----
    {
      int nn = gg >> 12, pim = gg & 4095;
#pragma unroll
      for (int i = 0; i < 16; ++i) {
        int c = q * 16 + i;
        float val = ov[i] + o2f[p64][c] + dv[i];
        int d = c & 31;
        long off = ((c < 32) ? (long)MAIN_RE : (long)MAIN_IM) + (long)(nn * 32 + d) * 4096 + pim;
        out[off] = val;
      }
      // prefetch next phase's out-RMW values
      if (ph < 3) {
        int gg2 = gg + 64;
        int nn2 = gg2 >> 12, pim2 = gg2 & 4095;
#pragma unroll
        for (int i = 0; i < 16; ++i) {
          int c = q * 16 + i;
          int d = c & 31;
          long off = ((c < 32) ? (long)MAIN_RE : (long)MAIN_IM) + (long)(nn2 * 32 + d) * 4096 + pim2;
          ov[i] = out[off];
        }
      }
    }
    __syncthreads();   // G: protect ho (o2f) reads vs next-phase dnp/decf writes
  }
}

extern "C" void kernel_launch(void* const* d_in, const int* in_sizes, int n_in,
                              void* d_out, int out_size, void* d_ws, size_t ws_size,
                              hipStream_t stream) {
  (void)in_sizes; (void)n_in; (void)out_size; (void)ws_size;
  const float* xre      = (const float*)d_in[0];
  const float* xim      = (const float*)d_in[1];
  const float* hre      = (const float*)d_in[2];
  const float* him      = (const float*)d_in[3];
  const float* flux_re  = (const float*)d_in[4];
  const float* flux_im  = (const float*)d_in[5];
  const float* dt_seq   = (const float*)d_in[6];
  const float* ln_s_g   = (const float*)d_in[7];
  const float* ln_s_b   = (const float*)d_in[8];
  const float* conv_w   = (const float*)d_in[9];
  const float* conv_b   = (const float*)d_in[10];
  const float* ln_t_g   = (const float*)d_in[11];
  const float* ln_t_b   = (const float*)d_in[12];
  const float* W_re     = (const float*)d_in[13];
  const float* W_im     = (const float*)d_in[14];
  const float* lam_flux = (const float*)d_in[15];
  const float* bf_re    = (const float*)d_in[16];
  const float* bf_im    = (const float*)d_in[17];
  const float* c_re     = (const float*)d_in[18];
  const float* c_im     = (const float*)d_in[19];
  const float* g_w      = (const float*)d_in[20];
  const float* g_b      = (const float*)d_in[21];
  const float* a_decay  = (const float*)d_in[22];
  const float* b_freq   = (const float*)d_in[23];
  const float* ffn_w1   = (const float*)d_in[24];
  const float* ffn_b1   = (const float*)d_in[25];
  const float* ffn_w2   = (const float*)d_in[26];
  const float* ffn_b2   = (const float*)d_in[27];
  const float* sg_w1    = (const float*)d_in[28];
  const float* sg_b1    = (const float*)d_in[29];
  const float* sg_dw    = (const float*)d_in[30];
  const float* sg_w2    = (const float*)d_in[31];
  const float* sg_b2    = (const float*)d_in[32];
  float* out = (float*)d_out;
  float* ws  = (float*)d_ws;

  k_invert<<<1, 256, 0, stream>>>(W_re, W_im, ws);
  k_wprep<<<144, 256, 0, stream>>>(conv_w, (unsigned short*)(ws + WS_WPK));
  k_eprep<<<8, 256, 0, stream>>>(W_re, W_im, sg_w1,
                                 (unsigned*)(ws + WS_WE), (unsigned*)(ws + WS_SG));
  k_ln_s<<<PIX / 256, 256, 0, stream>>>(xre, xim, ln_s_g, ln_s_b, ws);
  k_conv<<<768, 256, 0, stream>>>((const unsigned*)(ws + WS_XN),
                                  (const unsigned short*)(ws + WS_WPK),
                                  conv_b, xre, xim, out);
  k_xeig<<<768, 256, 0, stream>>>(out, (const unsigned*)(ws + WS_WE),
                                  (const unsigned*)(ws + WS_SG),
                                  ws + WS_XE, ws + WS_G1, sg_b1, ws + WS_PART);
  k_flux<<<1, 64, 0, stream>>>(ws, out, dt_seq, flux_re, flux_im, lam_flux,
                               bf_re, bf_im, c_re, c_im, g_w, g_b, a_decay, b_freq);
  k_gate<<<PIX / 128, 256, 0, stream>>>(ws + WS_G1, ws + WS_G2, sg_dw, sg_w2, sg_b2);
  k_scan<<<dim3(4096 / 256, 32, 2), 256, 0, stream>>>(ws + WS_XE, ws + WS_G2,
                                                      ws + WS_GATE, ws + WS_SRCR, ws + WS_SRCI,
                                                      ws + WS_OFR, ws + WS_OFI,
                                                      ws + WS_ODR, ws + WS_ODI,
                                                      hre, him, out);
  k_final<<<768, 256, 0, stream>>>(ws + WS_XE, out, (const unsigned*)(ws + WS_WIB),
                                   ln_t_g, ln_t_b, ffn_w1, ffn_b1, ffn_w2, ffn_b2);
}

// Round 16
// 302.082 us; speedup vs baseline: 1.2356x; 1.0732x over previous
//
#include <hip/hip_runtime.h>
#include <math.h>

#define BB 2
#define TT 24
#define DD 32
#define HWp 4096            // 64*64
#define NN (BB*TT)          // 48
#define PIX (NN*HWp)        // 196608
#define C2 (2*DD)           // 64

// d_out offsets (floats)
#define MAIN_RE 0
#define MAIN_IM (NN*DD*HWp)              // 6291456
#define HOUT_RE (2*NN*DD*HWp)            // 12582912
#define HOUT_IM (HOUT_RE + BB*HWp*DD)    // 12845056
#define FLUX_RE (HOUT_RE + 2*BB*HWp*DD)  // 13107200
#define FLUX_IM (FLUX_RE + BB*DD)        // 13107264

// ws offsets (floats)
#define WS_XN   0                        // PIX*32: xnb bf16 channels-last (conv input)
#define WS_XU   (WS_XN + PIX*32)         // PIX*32: xupd bf16 channels-last (u32 pairs)
#define WS_XE   (WS_XU + PIX*32)         // PIX*32 used: xe/u bf16 planes (ushort)
#define WS_G1   (WS_XE + PIX*C2)         // PIX*32  g1 planes f32
#define WS_G2   (WS_G1 + PIX*DD)         // PIX*32  spg planes f32
#define WS_WINV (WS_G2 + PIX*DD)         // 2048 f32
#define WS_SUMS (WS_WINV + 2048)         // 3072 (unused)
#define WS_GATE (WS_SUMS + 3072)         // 1536
#define WS_SRCR (WS_GATE + 1536)
#define WS_SRCI (WS_SRCR + 1536)
#define WS_ODR  (WS_SRCI + 1536)
#define WS_ODI  (WS_ODR + 1536)
#define WS_OFR  (WS_ODI + 1536)
#define WS_OFI  (WS_OFR + 1536)
#define WS_WPK  (WS_OFI + 1536)          // 36864 ushorts = 18432 floats
#define WS_PART (WS_WPK + 18432)         // 48*16*64 floats
#define WS_WE   (WS_PART + 49152)        // 2048 u32 eig weights [64][32]
#define WS_SG   (WS_WE + 2048)           // 1024 u32 sg1 weights [32][32]
#define WS_WIB  (WS_SG + 1024)           // 2048 u32 Winv packed [64][32]

typedef __attribute__((ext_vector_type(8))) short bf16x8;
typedef __attribute__((ext_vector_type(4))) float f32x4;
union FU { unsigned u[4]; bf16x8 f; };
union FU4 { uint4 v; unsigned u[4]; bf16x8 f; };

__device__ __forceinline__ float sigmoidf_(float x) { return 1.f / (1.f + expf(-x)); }
__device__ __forceinline__ float softplusf_(float x) { return log1pf(expf(x)); }
__device__ __forceinline__ unsigned short f2bf(float f) {
  unsigned u = __float_as_uint(f);
  return (unsigned short)((u + 0x7FFFu + ((u >> 16) & 1u)) >> 16);   // RNE
}
__device__ __forceinline__ unsigned pk2(float lo, float hi) {
  return (unsigned)f2bf(lo) | ((unsigned)f2bf(hi) << 16);
}
__device__ __forceinline__ float bf2f(unsigned short u) {
  return __uint_as_float((unsigned)u << 16);
}

// ---------------- Gauss-Jordan inverse of Wb (32x32 complex) + bf16 B-frag pack ----------
__global__ void k_invert(const float* __restrict__ Wre, const float* __restrict__ Wim,
                         float* __restrict__ ws) {
  __shared__ float Mre[32][64];
  __shared__ float Mim[32][64];
  __shared__ float fre[32], fim[32];
  __shared__ float pr_s, pi_s;
  __shared__ int piv_s;
  int tid = threadIdx.x;  // 256 threads
  for (int idx = tid; idx < 2048; idx += 256) {
    int i = idx >> 6, j = idx & 63;
    if (j < 32) { Mre[i][j] = Wre[i * 32 + j]; Mim[i][j] = Wim[i * 32 + j]; }
    else        { Mre[i][j] = (j - 32 == i) ? 1.f : 0.f; Mim[i][j] = 0.f; }
  }
  __syncthreads();
  for (int k = 0; k < 32; ++k) {
    if (tid == 0) {
      int best = k; float bm = fabsf(Mre[k][k]) + fabsf(Mim[k][k]);
      for (int r = k + 1; r < 32; ++r) {
        float m = fabsf(Mre[r][k]) + fabsf(Mim[r][k]);
        if (m > bm) { bm = m; best = r; }
      }
      piv_s = best;
    }
    __syncthreads();
    int pv = piv_s;
    if (pv != k && tid < 64) {
      float tr = Mre[k][tid], ti = Mim[k][tid];
      Mre[k][tid] = Mre[pv][tid]; Mim[k][tid] = Mim[pv][tid];
      Mre[pv][tid] = tr; Mim[pv][tid] = ti;
    }
    __syncthreads();
    if (tid == 0) {
      float a = Mre[k][k], b = Mim[k][k];
      float d = a * a + b * b;
      pr_s = a / d; pi_s = -b / d;
    }
    __syncthreads();
    float pr = pr_s, pi = pi_s;
    if (tid < 64) {
      float a = Mre[k][tid], b = Mim[k][tid];
      Mre[k][tid] = a * pr - b * pi;
      Mim[k][tid] = a * pi + b * pr;
    }
    __syncthreads();
    if (tid < 32) { fre[tid] = Mre[tid][k]; fim[tid] = Mim[tid][k]; }
    __syncthreads();
    for (int idx = tid; idx < 2048; idx += 256) {
      int i = idx >> 6, j = idx & 63;
      if (i != k) {
        float fr = fre[i], fi = fim[i];
        float ar = Mre[k][j], ai = Mim[k][j];
        Mre[i][j] -= fr * ar - fi * ai;
        Mim[i][j] -= fr * ai + fi * ar;
      }
    }
    __syncthreads();
  }
  for (int idx = tid; idx < 1024; idx += 256) {
    int e = idx >> 5, d = idx & 31;
    ws[WS_WINV + e * 32 + d] = Mre[e][32 + d];
    ws[WS_WINV + 1024 + e * 32 + d] = Mim[e][32 + d];
  }
  unsigned* wib = (unsigned*)(ws + WS_WIB);
  for (int idx = tid; idx < 2048; idx += 256) {
    int j = idx >> 5, kp = idx & 31;
    float v[2];
#pragma unroll
    for (int h = 0; h < 2; ++h) {
      int k = 2 * kp + h;
      float x;
      if (j < 32) x = (k < 32) ? Mre[k][32 + j] : -Mim[k - 32][32 + j];
      else        x = (k < 32) ? Mim[k][32 + (j - 32)] : Mre[k - 32][32 + (j - 32)];
      v[h] = x;
    }
    wib[idx] = pk2(v[0], v[1]);
  }
}

// ---------------- weight pre-pack: wpack[tap][oc][ci] bf16 <- conv_w[oc][ci][tap] f32 ----
__global__ void k_wprep(const float* __restrict__ w, unsigned short* __restrict__ wpk) {
  int idx = blockIdx.x * 256 + threadIdx.x;
  if (idx >= 9 * 64 * 64) return;
  int tap = idx >> 12;
  int rem = idx & 4095;
  int oc = rem >> 6, ci = rem & 63;
  wpk[idx] = f2bf(w[(oc * 64 + ci) * 9 + tap]);
}

// ---------------- eig + sg1 weight pre-pack (bf16 [N][Kpair] B-fragment layout) ----------
__global__ void k_eprep(const float* __restrict__ Wre, const float* __restrict__ Wim,
                        const float* __restrict__ sgw1,
                        unsigned* __restrict__ we, unsigned* __restrict__ sg) {
  int idx = blockIdx.x * 256 + threadIdx.x;
  if (idx < 2048) {
    int j = idx >> 5, kp = idx & 31;
    float v[2];
#pragma unroll
    for (int h = 0; h < 2; ++h) {
      int k = 2 * kp + h;
      float x;
      if (j < 32) x = (k < 32) ? Wre[k * 32 + j] : -Wim[(k - 32) * 32 + j];
      else        x = (k < 32) ? Wim[k * 32 + (j - 32)] : Wre[(k - 32) * 32 + (j - 32)];
      v[h] = x;
    }
    we[idx] = pk2(v[0], v[1]);
  }
  if (idx < 1024) {
    int oc = idx >> 5, kp = idx & 31;
    sg[idx] = pk2(sgw1[oc * 64 + 2 * kp], sgw1[oc * 64 + 2 * kp + 1]);
  }
}

// ---------------- spatial LayerNorm -> xn bf16 channels-last [n][pix][64] ----------------
__global__ void k_ln_s(const float* __restrict__ xre, const float* __restrict__ xim,
                       const float* __restrict__ g, const float* __restrict__ b,
                       float* __restrict__ ws) {
  int gid = blockIdx.x * 256 + threadIdx.x;
  if (gid >= PIX) return;
  int n = gid >> 12, p = gid & 4095;
  float v[64];
  float s = 0.f;
#pragma unroll
  for (int c = 0; c < 32; ++c) { v[c] = xre[(n * 32 + c) * 4096 + p]; s += v[c]; }
#pragma unroll
  for (int c = 0; c < 32; ++c) { v[32 + c] = xim[(n * 32 + c) * 4096 + p]; s += v[32 + c]; }
  float m = s * (1.f / 64.f);
  float vs = 0.f;
#pragma unroll
  for (int c = 0; c < 64; ++c) { float d = v[c] - m; vs += d * d; }
  float rs = rsqrtf(vs * (1.f / 64.f) + 1e-5f);
#pragma unroll
  for (int c = 0; c < 64; ++c) v[c] = (v[c] - m) * rs * g[c] + b[c];
  uint4* dst = (uint4*)ws + gid * 8;
#pragma unroll
  for (int q = 0; q < 8; ++q) {
    uint4 u;
    u.x = pk2(v[q * 8 + 0], v[q * 8 + 1]);
    u.y = pk2(v[q * 8 + 2], v[q * 8 + 3]);
    u.z = pk2(v[q * 8 + 4], v[q * 8 + 5]);
    u.w = pk2(v[q * 8 + 6], v[q * 8 + 7]);
    dst[q] = u;
  }
}

// ---------------- 3x3 conv 64->64 as 9 shifted bf16 MFMA GEMMs; xupd -> bf16 xub ---------
__global__ void __launch_bounds__(256) k_conv(
    const unsigned* __restrict__ xnb_u, const unsigned short* __restrict__ wpk,
    const float* __restrict__ bconv,
    const float* __restrict__ xre, const float* __restrict__ xim,
    unsigned* __restrict__ xub) {
  __shared__ unsigned xls[6 * 66 * 36];   // input tiles; later reused as xsb (ushort out)
  int bid = blockIdx.x;
  int n = bid >> 4;
  int y0 = (bid & 15) * 4;
  int tid = threadIdx.x;
  int wv = tid >> 6, l = tid & 63;
  int l15 = l & 15, l4 = l >> 4;

  const uint4* xnb4 = (const uint4*)xnb_u;
  for (int idx = tid; idx < 396; idx += 256) {
    int r = idx / 66, c = idx - r * 66;
    int y = y0 - 1 + r, x = c - 1;
    bool valid = ((unsigned)y < 64u) & ((unsigned)x < 64u);
    int pg = n * 4096 + y * 64 + x;
    uint4 z; z.x = z.y = z.z = z.w = 0u;
#pragma unroll
    for (int q = 0; q < 8; ++q) {
      uint4 v = valid ? xnb4[pg * 8 + q] : z;
      *(uint4*)&xls[idx * 36 + q * 4] = v;
    }
  }
  __syncthreads();

  f32x4 acc[4][4];
#pragma unroll
  for (int Nt = 0; Nt < 4; ++Nt) {
    float bb = bconv[Nt * 16 + l15];
#pragma unroll
    for (int mt = 0; mt < 4; ++mt) acc[mt][Nt] = (f32x4){bb, bb, bb, bb};
  }

  const uint4* wq = (const uint4*)wpk;
#pragma unroll
  for (int tap = 0; tap < 9; ++tap) {
    int ky = tap / 3, kx = tap - ky * 3;
    int rowbase = (wv + ky) * 66 + kx + l15;
#pragma unroll
    for (int ks = 0; ks < 2; ++ks) {
      FU4 B[4];
#pragma unroll
      for (int Nt = 0; Nt < 4; ++Nt)
        B[Nt].v = wq[tap * 512 + (Nt * 16 + l15) * 8 + ks * 4 + l4];
#pragma unroll
      for (int mt = 0; mt < 4; ++mt) {
        FU4 A;
        A.v = *(const uint4*)&xls[(rowbase + mt * 16) * 36 + ks * 16 + l4 * 4];
#pragma unroll
        for (int Nt = 0; Nt < 4; ++Nt)
          acc[mt][Nt] = __builtin_amdgcn_mfma_f32_16x16x32_bf16(A.f, B[Nt].f, acc[mt][Nt], 0, 0, 0);
      }
    }
  }
  __syncthreads();   // xls input reads done; reuse as ushort xsb [256][66]

  unsigned short (*xsb)[66] = (unsigned short(*)[66])xls;
#pragma unroll
  for (int Nt = 0; Nt < 4; ++Nt) {
    int oc = Nt * 16 + l15;
    int d = oc & 31;
    const float* resid = (oc < 32) ? xre : xim;
    const float* rsd = resid + (n * 32 + d) * 4096;
#pragma unroll
    for (int mt = 0; mt < 4; ++mt) {
      int lp0 = wv * 64 + mt * 16 + l4 * 4;
      int pixbase = y0 * 64 + lp0;
#pragma unroll
      for (int r = 0; r < 4; ++r)
        xsb[lp0 + r][oc] = f2bf(rsd[pixbase + r] + acc[mt][Nt][r]);
    }
  }
  __syncthreads();   // TBAA fence: ushort stores -> u32 reads

  // coalesced global write: 2048 uint4 per block
  int pixG0 = n * 4096 + y0 * 64;
#pragma unroll
  for (int i = 0; i < 8; ++i) {
    int idx = tid + 256 * i;
    int lp = idx >> 3, q4 = idx & 7;
    uint4 v;
    v.x = xls[lp * 33 + q4 * 4 + 0];
    v.y = xls[lp * 33 + q4 * 4 + 1];
    v.z = xls[lp * 33 + q4 * 4 + 2];
    v.w = xls[lp * 33 + q4 * 4 + 3];
    ((uint4*)xub)[(pixG0 + lp) * 8 + q4] = v;
  }
}

// ---------------- x_eig v5: A-frags direct from global xub; xe -> bf16 planes -------------
__global__ void __launch_bounds__(256) k_xeig(
    const unsigned* __restrict__ xub, const unsigned* __restrict__ weP,
    const unsigned* __restrict__ sgP, unsigned short* __restrict__ xeb,
    float* __restrict__ g1, const float* __restrict__ sgb1,
    float* __restrict__ part) {
  __shared__ unsigned WeT[64][35];
  __shared__ unsigned SgT[32][35];
  __shared__ unsigned xp[64][35];
  __shared__ float xef[64][67];

  int tid = threadIdx.x;
  int gbase = blockIdx.x * 256;
  int l = tid & 63, wv = tid >> 6;
  int l15 = l & 15, l4 = l >> 4;
  int p64 = l, q = wv;
  const uint4* xub4 = (const uint4*)xub;

  {
#pragma unroll
    for (int i = 0; i < 8; ++i) {
      int idx = tid + i * 256;
      WeT[idx >> 5][idx & 31] = weP[idx];
    }
#pragma unroll
    for (int i = 0; i < 4; ++i) {
      int idx = tid + i * 256;
      SgT[idx >> 5][idx & 31] = sgP[idx];
    }
  }
  float ssum[16];
#pragma unroll
  for (int i = 0; i < 16; ++i) ssum[i] = 0.f;
  __syncthreads();

  for (int ph = 0; ph < 4; ++ph) {
    int gg = gbase + ph * 64 + p64;
    int arow = wv * 16 + l15;
    int pixG = gbase + ph * 64 + arow;

    // layer 1: A directly from global (coalesced uint4)
    FU4 a0, a1;
    a0.v = xub4[pixG * 8 + l4];
    a1.v = xub4[pixG * 8 + 4 + l4];
#pragma unroll
    for (int Nt = 0; Nt < 4; ++Nt) {
      f32x4 acc = (f32x4){0.f, 0.f, 0.f, 0.f};
      FU b0f, b1f;
      int brow = Nt * 16 + l15;
#pragma unroll
      for (int jj = 0; jj < 4; ++jj) {
        b0f.u[jj] = WeT[brow][l4 * 4 + jj];
        b1f.u[jj] = WeT[brow][16 + l4 * 4 + jj];
      }
      acc = __builtin_amdgcn_mfma_f32_16x16x32_bf16(a0.f, b0f.f, acc, 0, 0, 0);
      acc = __builtin_amdgcn_mfma_f32_16x16x32_bf16(a1.f, b1f.f, acc, 0, 0, 0);
#pragma unroll
      for (int r = 0; r < 4; ++r)
        xef[wv * 16 + l4 * 4 + r][Nt * 16 + l15] = acc[r];
    }
    __syncthreads();   // B

    float xo[16];
#pragma unroll
    for (int i = 0; i < 16; ++i) {
      xo[i] = xef[p64][q * 16 + i];
      ssum[i] += xo[i];
      xeb[(q * 16 + i) * PIX + gg] = f2bf(xo[i]);
    }
#pragma unroll
    for (int ii = 0; ii < 8; ++ii)
      xp[p64][q * 8 + ii] = pk2(xo[2 * ii], xo[2 * ii + 1]);
    __syncthreads();   // C

    FU c0, c1;
#pragma unroll
    for (int jj = 0; jj < 4; ++jj) {
      c0.u[jj] = xp[arow][l4 * 4 + jj];
      c1.u[jj] = xp[arow][16 + l4 * 4 + jj];
    }
#pragma unroll
    for (int Nt = 0; Nt < 2; ++Nt) {
      float bb = sgb1[Nt * 16 + l15];
      f32x4 acc = (f32x4){bb, bb, bb, bb};
      FU b0f, b1f;
      int brow = Nt * 16 + l15;
#pragma unroll
      for (int jj = 0; jj < 4; ++jj) {
        b0f.u[jj] = SgT[brow][l4 * 4 + jj];
        b1f.u[jj] = SgT[brow][16 + l4 * 4 + jj];
      }
      acc = __builtin_amdgcn_mfma_f32_16x16x32_bf16(c0.f, b0f.f, acc, 0, 0, 0);
      acc = __builtin_amdgcn_mfma_f32_16x16x32_bf16(c1.f, b1f.f, acc, 0, 0, 0);
#pragma unroll
      for (int r = 0; r < 4; ++r) {
        float v = acc[r];
        xef[wv * 16 + l4 * 4 + r][Nt * 16 + l15] = v * sigmoidf_(v);
      }
    }
    __syncthreads();   // D

#pragma unroll
    for (int i = 0; i < 8; ++i)
      g1[(q * 8 + i) * PIX + gg] = xef[p64][q * 8 + i];
    __syncthreads();   // E: protect xp/xef reuse next phase
  }

#pragma unroll
  for (int i = 0; i < 16; ++i) {
    float v = ssum[i];
    v += __shfl_xor(v, 1);
    v += __shfl_xor(v, 2);
    v += __shfl_xor(v, 4);
    v += __shfl_xor(v, 8);
    v += __shfl_xor(v, 16);
    v += __shfl_xor(v, 32);
    if (l == 0) part[blockIdx.x * 64 + q * 16 + i] = v;
  }
}

// ---------------- flux scan (T=24) + all per-(b,t,d) coefficients ----------------
__global__ void k_flux(float* __restrict__ ws, float* __restrict__ out,
                       const float* __restrict__ dt_seq,
                       const float* __restrict__ flux_re, const float* __restrict__ flux_im,
                       const float* __restrict__ lam_flux,
                       const float* __restrict__ bf_re, const float* __restrict__ bf_im,
                       const float* __restrict__ c_re, const float* __restrict__ c_im,
                       const float* __restrict__ g_w, const float* __restrict__ g_b,
                       const float* __restrict__ a_decay, const float* __restrict__ b_freq) {
  int tid = threadIdx.x;
  if (tid >= 64) return;
  int b = tid >> 5, e = tid & 31;
  float sp_lf = softplusf_(lam_flux[e]);
  float lr = -softplusf_(a_decay[e]);
  float li = b_freq[e];
  float den = lr * lr + li * li;
  float bfr = bf_re[e], bfi = bf_im[e];
  float cr = c_re[e], ci = c_im[e];
  float fr = flux_re[b * 32 + e], fi = flux_im[b * 32 + e];
  const float* part = ws + WS_PART;
  for (int t = 0; t < 24; ++t) {
    int n = b * 24 + t;
    float dt = dt_seq[n];
    float A = expf(-sp_lf * dt);
    float xmr = 0.f, xmi = 0.f;
#pragma unroll
    for (int j = 0; j < 16; ++j) {
      xmr += part[(n * 16 + j) * 64 + e];
      xmi += part[(n * 16 + j) * 64 + 32 + e];
    }
    xmr *= (1.f / 4096.f);
    xmi *= (1.f / 4096.f);
    float Xr = (bfr * xmr - bfi * xmi) * dt;
    float Xi = (bfr * xmi + bfi * xmr) * dt;
    fr = A * fr + Xr;
    fi = A * fi + Xi;
    ws[WS_GATE + n * 32 + e] = sigmoidf_(fr * g_w[e] + g_b[e]);
    ws[WS_SRCR + n * 32 + e] = fr * cr - fi * ci;
    ws[WS_SRCI + n * 32 + e] = fr * ci + fi * cr;
    float er = expf(lr * dt);
    float odr = er * cosf(li * dt);
    float odi = er * sinf(li * dt);
    ws[WS_ODR + n * 32 + e] = odr;
    ws[WS_ODI + n * 32 + e] = odi;
    float nr = odr - 1.f, ni = odi;
    ws[WS_OFR + n * 32 + e] = (nr * lr + ni * li) / den;
    ws[WS_OFI + n * 32 + e] = (ni * lr - nr * li) / den;
  }
  out[FLUX_RE + b * 32 + e] = fr;
  out[FLUX_IM + b * 32 + e] = fi;
}

// ---------------- gate v3: dw 3x3 (shuffle stencil) + sg3 + sigmoid -> spg planes ---------
__global__ void __launch_bounds__(256) k_gate(
    const float* __restrict__ g1, float* __restrict__ spgP,
    const float* __restrict__ dw, const float* __restrict__ w2,
    const float* __restrict__ b2) {
  __shared__ float g2s[128][33];
  int tid = threadIdx.x;
  int l = tid & 63;
  int wv = tid >> 6;
  int r = wv >> 1, h = wv & 1;
  int pixbase = blockIdx.x * 128;
  int n = pixbase >> 12;
  int y = ((pixbase & 4095) >> 6) + r;
  int g = pixbase + r * 64 + l;
  int rp = r * 64 + l;

#pragma unroll
  for (int c = 0; c < 16; ++c) {
    int oc = h * 16 + c;
    const float* src = g1 + oc * PIX + n * 4096;
    const float* w = dw + oc * 9;        // uniform -> s_load
    float r0 = (y > 0)  ? src[(y - 1) * 64 + l] : 0.f;
    float r1 = src[y * 64 + l];
    float r2 = (y < 63) ? src[(y + 1) * 64 + l] : 0.f;
    float l0 = __shfl_up(r0, 1), t0 = __shfl_down(r0, 1);
    float l1 = __shfl_up(r1, 1), t1 = __shfl_down(r1, 1);
    float l2 = __shfl_up(r2, 1), t2 = __shfl_down(r2, 1);
    if (l == 0)  { l0 = 0.f; l1 = 0.f; l2 = 0.f; }
    if (l == 63) { t0 = 0.f; t1 = 0.f; t2 = 0.f; }
    float acc = 0.f;
    acc = fmaf(l0, w[0], acc); acc = fmaf(r0, w[1], acc); acc = fmaf(t0, w[2], acc);
    acc = fmaf(l1, w[3], acc); acc = fmaf(r1, w[4], acc); acc = fmaf(t1, w[5], acc);
    acc = fmaf(l2, w[6], acc); acc = fmaf(r2, w[7], acc); acc = fmaf(t2, w[8], acc);
    g2s[rp][oc] = acc;
  }
  __syncthreads();
  float g2a[32];
#pragma unroll
  for (int c = 0; c < 32; ++c) g2a[c] = g2s[rp][c];

#pragma unroll
  for (int c = 0; c < 16; ++c) {
    int e = h * 16 + c;
    float acc = b2[e];
#pragma unroll
    for (int k = 0; k < 32; ++k)
      acc = fmaf(g2a[k], w2[e * 32 + k], acc);     // uniform -> s_load
    spgP[e * PIX + g] = sigmoidf_(acc);
  }
}

// ---------------- fused forcing + temporal scan over T=24 (bf16 planes), emit h_out -------
__global__ void __launch_bounds__(256) k_scan(
    unsigned short* __restrict__ ub, const float* __restrict__ spgP,
    const float* __restrict__ gate, const float* __restrict__ srcr,
    const float* __restrict__ srci, const float* __restrict__ ofr_p,
    const float* __restrict__ ofi_p, const float* __restrict__ odr_p,
    const float* __restrict__ odi_p,
    const float* __restrict__ hre, const float* __restrict__ him,
    float* __restrict__ out) {
  int p = blockIdx.x * 256 + threadIdx.x;   // 0..4095
  int e = blockIdx.y;                        // 0..31 (block-uniform)
  int b = blockIdx.z;                        // 0..1
  float ur = 0.f, ui = 0.f;
  for (int t = 0; t < 24; ++t) {
    int n = b * 24 + t;
    int ie = n * 32 + e;
    int idx  = e * PIX + n * 4096 + p;
    int idxi = (32 + e) * PIX + n * 4096 + p;
    float gc = gate[ie] * spgP[idx];
    float xr = bf2f(ub[idx]), xi = bf2f(ub[idxi]);
    float om = 1.f - gc;
    float fr2 = xr * gc + srcr[ie] * om;
    float fi2 = xi * gc + srci[ie] * om;
    float ofr = ofr_p[ie], ofi = ofi_p[ie];
    float utr = fr2 * ofr - fi2 * ofi;
    float uti = fr2 * ofi + fi2 * ofr;
    if (t == 0) {
      int hb = (b * 4096 + p) * 32 + e;
      float hr = hre[hb], hi = him[hb];
      float odr0 = odr_p[ie], odi0 = odi_p[ie];
      utr += hr * odr0 - hi * odi0;
      uti += hr * odi0 + hi * odr0;
    }
    float ar = odr_p[ie], ai = odi_p[ie];
    float nr = ar * ur - ai * ui + utr;
    float ni = ar * ui + ai * ur + uti;
    ur = nr; ui = ni;
    ub[idx] = f2bf(ur);
    ub[idxi] = f2bf(ui);
  }
  out[HOUT_RE + (b * 4096 + p) * 32 + e] = ur;
  out[HOUT_IM + (b * 4096 + p) * 32 + e] = ui;
}

// ---------------- dec(Winv MFMA) + LN_t + FFN MFMA + z = xupd + dec + delta ---------------
// u input: bf16 planes (direct pair-pack). xupd: bf16 channels-last. out: pure stores.
__global__ void __launch_bounds__(256) k_final(
    const unsigned short* __restrict__ ub, const unsigned* __restrict__ xub,
    float* __restrict__ out, const unsigned* __restrict__ wibP,
    const float* __restrict__ lg, const float* __restrict__ lb,
    const float* __restrict__ w1, const float* __restrict__ b1,
    const float* __restrict__ w2, const float* __restrict__ b2) {
  __shared__ unsigned wiT[64][35];
  __shared__ unsigned w1T[128][35];
  __shared__ unsigned w2T[64][67];
  __shared__ unsigned dnp[64][35];
  __shared__ unsigned ho[64][67];
  __shared__ float ps1[64][5];
  __shared__ float ps2[64][5];

  int tid = threadIdx.x;
  int gbase = blockIdx.x * 256;
  int l = tid & 63, wv = tid >> 6;
  int l15 = l & 15, l4 = l >> 4;
  int p64 = l, q = wv;
  const uint4* xub4 = (const uint4*)xub;

  {
#pragma unroll
    for (int i = 0; i < 8; ++i) {
      int idx = tid + i * 256;
      wiT[idx >> 5][idx & 31] = wibP[idx];
    }
    int hid = tid & 127, half = tid >> 7;
#pragma unroll
    for (int i = 0; i < 16; ++i) {
      int cp = half * 16 + i;
      w1T[hid][cp] = pk2(w1[(2 * cp) * 128 + hid], w1[(2 * cp + 1) * 128 + hid]);
    }
#pragma unroll
    for (int i = 0; i < 16; ++i) {
      int hp = wv * 16 + i;
      w2T[l][hp] = pk2(w2[(2 * hp) * 64 + l], w2[(2 * hp + 1) * 64 + l]);
    }
  }
  float bb1v[8], bb2v[4];
#pragma unroll
  for (int Hn = 0; Hn < 8; ++Hn) bb1v[Hn] = b1[Hn * 16 + l15];
#pragma unroll
  for (int On = 0; On < 4; ++On) bb2v[On] = b2[On * 16 + l15];

  // prefetch phase-0 u (packed pairs) and xupd
  unsigned uvp[8];
  FU4 xa, xb;
  {
    int gg = gbase + p64;
#pragma unroll
    for (int ii = 0; ii < 8; ++ii) {
      int c0 = q * 16 + 2 * ii;
      unsigned lo = ub[c0 * PIX + gg];
      unsigned hi = ub[(c0 + 1) * PIX + gg];
      uvp[ii] = lo | (hi << 16);
    }
    xa.v = xub4[gg * 8 + q * 2];
    xb.v = xub4[gg * 8 + q * 2 + 1];
  }
  __syncthreads();

  for (int ph = 0; ph < 4; ++ph) {
    int gg = gbase + ph * 64 + p64;
    int arow = wv * 16 + l15;

#pragma unroll
    for (int ii = 0; ii < 8; ++ii)
      dnp[p64][q * 8 + ii] = uvp[ii];
    // prefetch next phase's u pairs
    if (ph < 3) {
      int gg2 = gg + 64;
#pragma unroll
      for (int ii = 0; ii < 8; ++ii) {
        int c0 = q * 16 + 2 * ii;
        unsigned lo = ub[c0 * PIX + gg2];
        unsigned hi = ub[(c0 + 1) * PIX + gg2];
        uvp[ii] = lo | (hi << 16);
      }
    }
    __syncthreads();   // A

    {
      FU a0, a1;
#pragma unroll
      for (int jj = 0; jj < 4; ++jj) {
        a0.u[jj] = dnp[arow][l4 * 4 + jj];
        a1.u[jj] = dnp[arow][16 + l4 * 4 + jj];
      }
      float (*decf)[67] = (float(*)[67])ho;
#pragma unroll
      for (int Nt = 0; Nt < 4; ++Nt) {
        f32x4 acc = (f32x4){0.f, 0.f, 0.f, 0.f};
        FU b0f, b1f;
        int brow = Nt * 16 + l15;
#pragma unroll
        for (int jj = 0; jj < 4; ++jj) {
          b0f.u[jj] = wiT[brow][l4 * 4 + jj];
          b1f.u[jj] = wiT[brow][16 + l4 * 4 + jj];
        }
        acc = __builtin_amdgcn_mfma_f32_16x16x32_bf16(a0.f, b0f.f, acc, 0, 0, 0);
        acc = __builtin_amdgcn_mfma_f32_16x16x32_bf16(a1.f, b1f.f, acc, 0, 0, 0);
#pragma unroll
        for (int r = 0; r < 4; ++r)
          decf[wv * 16 + l4 * 4 + r][Nt * 16 + l15] = acc[r];
      }
    }
    __syncthreads();   // B

    float dv[16];
    float s1 = 0.f, s2 = 0.f;
    {
      float (*decf)[67] = (float(*)[67])ho;
#pragma unroll
      for (int i = 0; i < 16; ++i) {
        dv[i] = decf[p64][q * 16 + i];
        s1 += dv[i];
        s2 += dv[i] * dv[i];
      }
    }
    ps1[p64][q] = s1;
    ps2[p64][q] = s2;
    __syncthreads();   // C
    float m  = (ps1[p64][0] + ps1[p64][1] + ps1[p64][2] + ps1[p64][3]) * (1.f / 64.f);
    float e2 = (ps2[p64][0] + ps2[p64][1] + ps2[p64][2] + ps2[p64][3]) * (1.f / 64.f);
    float rs = rsqrtf(e2 - m * m + 1e-5f);
#pragma unroll
    for (int ii = 0; ii < 8; ++ii) {
      int c0 = q * 16 + 2 * ii;
      float a = (dv[2 * ii]     - m) * rs * lg[c0]     + lb[c0];
      float bvl = (dv[2 * ii + 1] - m) * rs * lg[c0 + 1] + lb[c0 + 1];
      dnp[p64][q * 8 + ii] = pk2(a, bvl);
    }
    __syncthreads();   // D

    FU a0, a1;
#pragma unroll
    for (int jj = 0; jj < 4; ++jj) {
      a0.u[jj] = dnp[arow][l4 * 4 + jj];
      a1.u[jj] = dnp[arow][16 + l4 * 4 + jj];
    }
    f32x4 acc[8];
#pragma unroll
    for (int Hn = 0; Hn < 8; ++Hn) {
      float bb = bb1v[Hn];
      acc[Hn] = (f32x4){bb, bb, bb, bb};
      FU b0f, b1f;
      int brow = Hn * 16 + l15;
#pragma unroll
      for (int jj = 0; jj < 4; ++jj) {
        b0f.u[jj] = w1T[brow][l4 * 4 + jj];
        b1f.u[jj] = w1T[brow][16 + l4 * 4 + jj];
      }
      acc[Hn] = __builtin_amdgcn_mfma_f32_16x16x32_bf16(a0.f, b0f.f, acc[Hn], 0, 0, 0);
      acc[Hn] = __builtin_amdgcn_mfma_f32_16x16x32_bf16(a1.f, b1f.f, acc[Hn], 0, 0, 0);
    }
    unsigned short (*hidb)[134] = (unsigned short(*)[134])ho;
#pragma unroll
    for (int Hn = 0; Hn < 8; ++Hn) {
#pragma unroll
      for (int r = 0; r < 4; ++r) {
        float v = acc[Hn][r];
        v = v * sigmoidf_(v);
        hidb[wv * 16 + l4 * 4 + r][Hn * 16 + l15] = f2bf(v);
      }
    }
    __syncthreads();   // E: TBAA fence (ushort stores -> u32 loads)

    FU a2[4];
#pragma unroll
    for (int kk = 0; kk < 4; ++kk)
#pragma unroll
      for (int jj = 0; jj < 4; ++jj)
        a2[kk].u[jj] = ((unsigned(*)[67])ho)[arow][kk * 16 + l4 * 4 + jj];
    f32x4 acc2[4];
#pragma unroll
    for (int On = 0; On < 4; ++On) {
      float bb = bb2v[On];
      acc2[On] = (f32x4){bb, bb, bb, bb};
#pragma unroll
      for (int kk = 0; kk < 4; ++kk) {
        FU b2f;
#pragma unroll
        for (int jj = 0; jj < 4; ++jj)
          b2f.u[jj] = w2T[On * 16 + l15][kk * 16 + l4 * 4 + jj];
        acc2[On] = __builtin_amdgcn_mfma_f32_16x16x32_bf16(a2[kk].f, b2f.f, acc2[On], 0, 0, 0);
      }
    }
    float (*o2f)[67] = (float(*)[67])ho;
#pragma unroll
    for (int On = 0; On < 4; ++On)
#pragma unroll
      for (int r = 0; r < 4; ++r)
        o2f[wv * 16 + l4 * 4 + r][On * 16 + l15] = acc2[On][r];
    __syncthreads();   // F

    // ---- epilogue: pure stores; xupd from prefetched bf16 pairs ----
    {
      int nn = gg >> 12, pim = gg & 4095;
#pragma unroll
      for (int ii = 0; ii < 8; ++ii) {
        unsigned w = (ii < 4) ? xa.u[ii] : xb.u[ii - 4];
        float x0 = __uint_as_float(w << 16);
        float x1 = __uint_as_float(w & 0xFFFF0000u);
        int c0 = q * 16 + 2 * ii;
#pragma unroll
        for (int h = 0; h < 2; ++h) {
          int c = c0 + h;
          float xv = (h == 0) ? x0 : x1;
          float val = xv + o2f[p64][c] + dv[2 * ii + h];
          int d = c & 31;
          long off = ((c < 32) ? (long)MAIN_RE : (long)MAIN_IM) + (long)(nn * 32 + d) * 4096 + pim;
          out[off] = val;
        }
      }
      // prefetch next phase's xupd
      if (ph < 3) {
        int gg2 = gg + 64;
        xa.v = xub4[gg2 * 8 + q * 2];
        xb.v = xub4[gg2 * 8 + q * 2 + 1];
      }
    }
    __syncthreads();   // G: protect ho (o2f) reads vs next-phase dnp/decf writes
  }
}

extern "C" void kernel_launch(void* const* d_in, const int* in_sizes, int n_in,
                              void* d_out, int out_size, void* d_ws, size_t ws_size,
                              hipStream_t stream) {
  (void)in_sizes; (void)n_in; (void)out_size; (void)ws_size;
  const float* xre      = (const float*)d_in[0];
  const float* xim      = (const float*)d_in[1];
  const float* hre      = (const float*)d_in[2];
  const float* him      = (const float*)d_in[3];
  const float* flux_re  = (const float*)d_in[4];
  const float* flux_im  = (const float*)d_in[5];
  const float* dt_seq   = (const float*)d_in[6];
  const float* ln_s_g   = (const float*)d_in[7];
  const float* ln_s_b   = (const float*)d_in[8];
  const float* conv_w   = (const float*)d_in[9];
  const float* conv_b   = (const float*)d_in[10];
  const float* ln_t_g   = (const float*)d_in[11];
  const float* ln_t_b   = (const float*)d_in[12];
  const float* W_re     = (const float*)d_in[13];
  const float* W_im     = (const float*)d_in[14];
  const float* lam_flux = (const float*)d_in[15];
  const float* bf_re    = (const float*)d_in[16];
  const float* bf_im    = (const float*)d_in[17];
  const float* c_re     = (const float*)d_in[18];
  const float* c_im     = (const float*)d_in[19];
  const float* g_w      = (const float*)d_in[20];
  const float* g_b      = (const float*)d_in[21];
  const float* a_decay  = (const float*)d_in[22];
  const float* b_freq   = (const float*)d_in[23];
  const float* ffn_w1   = (const float*)d_in[24];
  const float* ffn_b1   = (const float*)d_in[25];
  const float* ffn_w2   = (const float*)d_in[26];
  const float* ffn_b2   = (const float*)d_in[27];
  const float* sg_w1    = (const float*)d_in[28];
  const float* sg_b1    = (const float*)d_in[29];
  const float* sg_dw    = (const float*)d_in[30];
  const float* sg_w2    = (const float*)d_in[31];
  const float* sg_b2    = (const float*)d_in[32];
  float* out = (float*)d_out;
  float* ws  = (float*)d_ws;

  unsigned* xub = (unsigned*)(ws + WS_XU);
  unsigned short* xeb = (unsigned short*)(ws + WS_XE);

  k_invert<<<1, 256, 0, stream>>>(W_re, W_im, ws);
  k_wprep<<<144, 256, 0, stream>>>(conv_w, (unsigned short*)(ws + WS_WPK));
  k_eprep<<<8, 256, 0, stream>>>(W_re, W_im, sg_w1,
                                 (unsigned*)(ws + WS_WE), (unsigned*)(ws + WS_SG));
  k_ln_s<<<PIX / 256, 256, 0, stream>>>(xre, xim, ln_s_g, ln_s_b, ws);
  k_conv<<<768, 256, 0, stream>>>((const unsigned*)(ws + WS_XN),
                                  (const unsigned short*)(ws + WS_WPK),
                                  conv_b, xre, xim, xub);
  k_xeig<<<768, 256, 0, stream>>>(xub, (const unsigned*)(ws + WS_WE),
                                  (const unsigned*)(ws + WS_SG),
                                  xeb, ws + WS_G1, sg_b1, ws + WS_PART);
  k_flux<<<1, 64, 0, stream>>>(ws, out, dt_seq, flux_re, flux_im, lam_flux,
                               bf_re, bf_im, c_re, c_im, g_w, g_b, a_decay, b_freq);
  k_gate<<<PIX / 128, 256, 0, stream>>>(ws + WS_G1, ws + WS_G2, sg_dw, sg_w2, sg_b2);
  k_scan<<<dim3(4096 / 256, 32, 2), 256, 0, stream>>>(xeb, ws + WS_G2,
                                                      ws + WS_GATE, ws + WS_SRCR, ws + WS_SRCI,
                                                      ws + WS_OFR, ws + WS_OFI,
                                                      ws + WS_ODR, ws + WS_ODI,
                                                      hre, him, out);
  k_final<<<768, 256, 0, stream>>>(xeb, xub, out, (const unsigned*)(ws + WS_WIB),
                                   ln_t_g, ln_t_b, ffn_w1, ffn_b1, ffn_w2, ffn_b2);
}

// Round 17
// 293.200 us; speedup vs baseline: 1.2730x; 1.0303x over previous
//
#include <hip/hip_runtime.h>
#include <math.h>

#define BB 2
#define TT 24
#define DD 32
#define HWp 4096            // 64*64
#define NN (BB*TT)          // 48
#define PIX (NN*HWp)        // 196608
#define C2 (2*DD)           // 64

// d_out offsets (floats)
#define MAIN_RE 0
#define MAIN_IM (NN*DD*HWp)              // 6291456
#define HOUT_RE (2*NN*DD*HWp)            // 12582912
#define HOUT_IM (HOUT_RE + BB*HWp*DD)    // 12845056
#define FLUX_RE (HOUT_RE + 2*BB*HWp*DD)  // 13107200
#define FLUX_IM (FLUX_RE + BB*DD)        // 13107264

// ws offsets (floats)
#define WS_XN   0                        // PIX*32: xnb bf16 channels-last (conv input)
#define WS_XU   (WS_XN + PIX*32)         // PIX*32: xupd bf16 channels-last (u32 pairs)
#define WS_XE   (WS_XU + PIX*32)         // PIX*32 used: xe/u bf16 planes (ushort)
#define WS_G1   (WS_XE + PIX*C2)         // PIX*32  g1 planes f32
#define WS_G2   (WS_G1 + PIX*DD)         // PIX*32  spg planes f32
#define WS_WINV (WS_G2 + PIX*DD)         // 2048 f32 (unused)
#define WS_SUMS (WS_WINV + 2048)         // 3072 (unused)
#define WS_GATE (WS_SUMS + 3072)         // 1536
#define WS_SRCR (WS_GATE + 1536)
#define WS_SRCI (WS_SRCR + 1536)
#define WS_ODR  (WS_SRCI + 1536)
#define WS_ODI  (WS_ODR + 1536)
#define WS_OFR  (WS_ODI + 1536)
#define WS_OFI  (WS_OFR + 1536)
#define WS_WPK  (WS_OFI + 1536)          // 36864 ushorts = 18432 floats
#define WS_PART (WS_WPK + 18432)         // 48*16*64 floats
#define WS_WE   (WS_PART + 49152)        // 2048 u32 eig weights [64][32]
#define WS_SG   (WS_WE + 2048)           // 1024 u32 sg1 weights [32][32]
#define WS_WIB  (WS_SG + 1024)           // 2048 u32 Winv packed [64][32]

typedef __attribute__((ext_vector_type(8))) short bf16x8;
typedef __attribute__((ext_vector_type(4))) float f32x4;
union FU { unsigned u[4]; bf16x8 f; };
union FU4 { uint4 v; unsigned u[4]; bf16x8 f; };

__device__ __forceinline__ float sigmoidf_(float x) { return 1.f / (1.f + expf(-x)); }
__device__ __forceinline__ float softplusf_(float x) { return log1pf(expf(x)); }
__device__ __forceinline__ unsigned short f2bf(float f) {
  unsigned u = __float_as_uint(f);
  return (unsigned short)((u + 0x7FFFu + ((u >> 16) & 1u)) >> 16);   // RNE
}
__device__ __forceinline__ unsigned pk2(float lo, float hi) {
  return (unsigned)f2bf(lo) | ((unsigned)f2bf(hi) << 16);
}
__device__ __forceinline__ float bf2f(unsigned short u) {
  return __uint_as_float((unsigned)u << 16);
}

// ---------------- fused prep: LN (blocks 0..767) || invert (768) || wprep (769..784)
//                  || eprep (785..788). Invert rides free under the LN pass.
__global__ void __launch_bounds__(256) k_prep(
    const float* __restrict__ xre, const float* __restrict__ xim,
    const float* __restrict__ g, const float* __restrict__ b,
    const float* __restrict__ Wre, const float* __restrict__ Wim,
    const float* __restrict__ conv_w, const float* __restrict__ sgw1,
    float* __restrict__ ws) {
  __shared__ float Mre[32][64];
  __shared__ float Mim[32][64];
  __shared__ float fre[32], fim[32];
  __shared__ int piv_s;
  int bid = blockIdx.x;
  int tid = threadIdx.x;

  if (bid < 768) {
    // ---- spatial LayerNorm -> xnb bf16 channels-last ----
    int gid = bid * 256 + tid;
    int n = gid >> 12, p = gid & 4095;
    float v[64];
    float s = 0.f;
#pragma unroll
    for (int c = 0; c < 32; ++c) { v[c] = xre[(n * 32 + c) * 4096 + p]; s += v[c]; }
#pragma unroll
    for (int c = 0; c < 32; ++c) { v[32 + c] = xim[(n * 32 + c) * 4096 + p]; s += v[32 + c]; }
    float m = s * (1.f / 64.f);
    float vs = 0.f;
#pragma unroll
    for (int c = 0; c < 64; ++c) { float d = v[c] - m; vs += d * d; }
    float rs = rsqrtf(vs * (1.f / 64.f) + 1e-5f);
#pragma unroll
    for (int c = 0; c < 64; ++c) v[c] = (v[c] - m) * rs * g[c] + b[c];
    uint4* dst = (uint4*)ws + gid * 8;
#pragma unroll
    for (int q = 0; q < 8; ++q) {
      uint4 u;
      u.x = pk2(v[q * 8 + 0], v[q * 8 + 1]);
      u.y = pk2(v[q * 8 + 2], v[q * 8 + 3]);
      u.z = pk2(v[q * 8 + 4], v[q * 8 + 5]);
      u.w = pk2(v[q * 8 + 6], v[q * 8 + 7]);
      dst[q] = u;
    }
    return;
  }

  if (bid == 768) {
    // ---- Gauss-Jordan inverse (parallel pivot argmax) + bf16 B-frag pack ----
    for (int idx = tid; idx < 2048; idx += 256) {
      int i = idx >> 6, j = idx & 63;
      if (j < 32) { Mre[i][j] = Wre[i * 32 + j]; Mim[i][j] = Wim[i * 32 + j]; }
      else        { Mre[i][j] = (j - 32 == i) ? 1.f : 0.f; Mim[i][j] = 0.f; }
    }
    __syncthreads();
    for (int k = 0; k < 32; ++k) {
      if (tid < 64) {
        int r = tid & 31;
        float mm = (r >= k) ? (fabsf(Mre[r][k]) + fabsf(Mim[r][k])) : -1.f;
        int best = r;
#pragma unroll
        for (int off = 16; off > 0; off >>= 1) {
          float m2 = __shfl_xor(mm, off);
          int b2 = __shfl_xor(best, off);
          if (m2 > mm || (m2 == mm && b2 < best)) { mm = m2; best = b2; }
        }
        if (tid == 0) piv_s = best;
      }
      __syncthreads();
      int pv = piv_s;
      if (pv != k && tid < 64) {
        float tr = Mre[k][tid], ti = Mim[k][tid];
        Mre[k][tid] = Mre[pv][tid]; Mim[k][tid] = Mim[pv][tid];
        Mre[pv][tid] = tr; Mim[pv][tid] = ti;
      }
      __syncthreads();
      // reciprocal computed redundantly by all threads (broadcast LDS read)
      float a = Mre[k][k], bq = Mim[k][k];
      float dd = a * a + bq * bq;
      float pr = a / dd, pi = -bq / dd;
      if (tid < 64) {
        float x = Mre[k][tid], y = Mim[k][tid];
        Mre[k][tid] = x * pr - y * pi;
        Mim[k][tid] = x * pi + y * pr;
      }
      __syncthreads();
      if (tid < 32) { fre[tid] = Mre[tid][k]; fim[tid] = Mim[tid][k]; }
      __syncthreads();
      for (int idx = tid; idx < 2048; idx += 256) {
        int i = idx >> 6, j = idx & 63;
        if (i != k) {
          float fr = fre[i], fi = fim[i];
          float ar = Mre[k][j], ai = Mim[k][j];
          Mre[i][j] -= fr * ar - fi * ai;
          Mim[i][j] -= fr * ai + fi * ar;
        }
      }
      __syncthreads();
    }
    unsigned* wib = (unsigned*)(ws + WS_WIB);
    for (int idx = tid; idx < 2048; idx += 256) {
      int j = idx >> 5, kp = idx & 31;
      float v[2];
#pragma unroll
      for (int h = 0; h < 2; ++h) {
        int k = 2 * kp + h;
        float x;
        if (j < 32) x = (k < 32) ? Mre[k][32 + j] : -Mim[k - 32][32 + j];
        else        x = (k < 32) ? Mim[k][32 + (j - 32)] : Mre[k - 32][32 + (j - 32)];
        v[h] = x;
      }
      wib[idx] = pk2(v[0], v[1]);
    }
    return;
  }

  if (bid <= 784) {
    // ---- conv weight pack slice: wpk[tap][oc][ci] bf16 ----
    int slice = bid - 769;   // 0..15
    unsigned short* wpk = (unsigned short*)(ws + WS_WPK);
#pragma unroll
    for (int i = 0; i < 9; ++i) {
      int idx = slice * 2304 + i * 256 + tid;
      int tap = idx >> 12;
      int rem = idx & 4095;
      int oc = rem >> 6, ci = rem & 63;
      wpk[idx] = f2bf(conv_w[(oc * 64 + ci) * 9 + tap]);
    }
    return;
  }

  // ---- eig + sg1 weight pack (blocks 785..788) ----
  {
    int t = (bid - 785) * 256 + tid;   // 0..1023
    unsigned* we = (unsigned*)(ws + WS_WE);
    unsigned* sg = (unsigned*)(ws + WS_SG);
    {
      int oc = t >> 5, kp = t & 31;
      sg[t] = pk2(sgw1[oc * 64 + 2 * kp], sgw1[oc * 64 + 2 * kp + 1]);
    }
#pragma unroll
    for (int h2 = 0; h2 < 2; ++h2) {
      int idx = t + h2 * 1024;
      int j = idx >> 5, kp = idx & 31;
      float v[2];
#pragma unroll
      for (int h = 0; h < 2; ++h) {
        int k = 2 * kp + h;
        float x;
        if (j < 32) x = (k < 32) ? Wre[k * 32 + j] : -Wim[(k - 32) * 32 + j];
        else        x = (k < 32) ? Wim[k * 32 + (j - 32)] : Wre[(k - 32) * 32 + (j - 32)];
        v[h] = x;
      }
      we[idx] = pk2(v[0], v[1]);
    }
  }
}

// ---------------- 3x3 conv 64->64 as 9 shifted bf16 MFMA GEMMs; xupd -> bf16 xub ---------
__global__ void __launch_bounds__(256) k_conv(
    const unsigned* __restrict__ xnb_u, const unsigned short* __restrict__ wpk,
    const float* __restrict__ bconv,
    const float* __restrict__ xre, const float* __restrict__ xim,
    unsigned* __restrict__ xub) {
  __shared__ unsigned xls[6 * 66 * 36];   // input tiles; later reused as xsb (ushort out)
  int bid = blockIdx.x;
  int n = bid >> 4;
  int y0 = (bid & 15) * 4;
  int tid = threadIdx.x;
  int wv = tid >> 6, l = tid & 63;
  int l15 = l & 15, l4 = l >> 4;

  const uint4* xnb4 = (const uint4*)xnb_u;
  for (int idx = tid; idx < 396; idx += 256) {
    int r = idx / 66, c = idx - r * 66;
    int y = y0 - 1 + r, x = c - 1;
    bool valid = ((unsigned)y < 64u) & ((unsigned)x < 64u);
    int pg = n * 4096 + y * 64 + x;
    uint4 z; z.x = z.y = z.z = z.w = 0u;
#pragma unroll
    for (int q = 0; q < 8; ++q) {
      uint4 v = valid ? xnb4[pg * 8 + q] : z;
      *(uint4*)&xls[idx * 36 + q * 4] = v;
    }
  }
  __syncthreads();

  f32x4 acc[4][4];
#pragma unroll
  for (int Nt = 0; Nt < 4; ++Nt) {
    float bb = bconv[Nt * 16 + l15];
#pragma unroll
    for (int mt = 0; mt < 4; ++mt) acc[mt][Nt] = (f32x4){bb, bb, bb, bb};
  }

  const uint4* wq = (const uint4*)wpk;
#pragma unroll
  for (int tap = 0; tap < 9; ++tap) {
    int ky = tap / 3, kx = tap - ky * 3;
    int rowbase = (wv + ky) * 66 + kx + l15;
#pragma unroll
    for (int ks = 0; ks < 2; ++ks) {
      FU4 B[4];
#pragma unroll
      for (int Nt = 0; Nt < 4; ++Nt)
        B[Nt].v = wq[tap * 512 + (Nt * 16 + l15) * 8 + ks * 4 + l4];
#pragma unroll
      for (int mt = 0; mt < 4; ++mt) {
        FU4 A;
        A.v = *(const uint4*)&xls[(rowbase + mt * 16) * 36 + ks * 16 + l4 * 4];
#pragma unroll
        for (int Nt = 0; Nt < 4; ++Nt)
          acc[mt][Nt] = __builtin_amdgcn_mfma_f32_16x16x32_bf16(A.f, B[Nt].f, acc[mt][Nt], 0, 0, 0);
      }
    }
  }
  __syncthreads();   // xls input reads done; reuse as ushort xsb [256][66]

  unsigned short (*xsb)[66] = (unsigned short(*)[66])xls;
#pragma unroll
  for (int Nt = 0; Nt < 4; ++Nt) {
    int oc = Nt * 16 + l15;
    int d = oc & 31;
    const float* resid = (oc < 32) ? xre : xim;
    const float* rsd = resid + (n * 32 + d) * 4096;
#pragma unroll
    for (int mt = 0; mt < 4; ++mt) {
      int lp0 = wv * 64 + mt * 16 + l4 * 4;
      int pixbase = y0 * 64 + lp0;
#pragma unroll
      for (int r = 0; r < 4; ++r)
        xsb[lp0 + r][oc] = f2bf(rsd[pixbase + r] + acc[mt][Nt][r]);
    }
  }
  __syncthreads();   // TBAA fence: ushort stores -> u32 reads

  int pixG0 = n * 4096 + y0 * 64;
#pragma unroll
  for (int i = 0; i < 8; ++i) {
    int idx = tid + 256 * i;
    int lp = idx >> 3, q4 = idx & 7;
    uint4 v;
    v.x = xls[lp * 33 + q4 * 4 + 0];
    v.y = xls[lp * 33 + q4 * 4 + 1];
    v.z = xls[lp * 33 + q4 * 4 + 2];
    v.w = xls[lp * 33 + q4 * 4 + 3];
    ((uint4*)xub)[(pixG0 + lp) * 8 + q4] = v;
  }
}

// ---------------- x_eig v5: A-frags direct from global xub; xe -> bf16 planes -------------
__global__ void __launch_bounds__(256) k_xeig(
    const unsigned* __restrict__ xub, const unsigned* __restrict__ weP,
    const unsigned* __restrict__ sgP, unsigned short* __restrict__ xeb,
    float* __restrict__ g1, const float* __restrict__ sgb1,
    float* __restrict__ part) {
  __shared__ unsigned WeT[64][35];
  __shared__ unsigned SgT[32][35];
  __shared__ unsigned xp[64][35];
  __shared__ float xef[64][67];

  int tid = threadIdx.x;
  int gbase = blockIdx.x * 256;
  int l = tid & 63, wv = tid >> 6;
  int l15 = l & 15, l4 = l >> 4;
  int p64 = l, q = wv;
  const uint4* xub4 = (const uint4*)xub;

  {
#pragma unroll
    for (int i = 0; i < 8; ++i) {
      int idx = tid + i * 256;
      WeT[idx >> 5][idx & 31] = weP[idx];
    }
#pragma unroll
    for (int i = 0; i < 4; ++i) {
      int idx = tid + i * 256;
      SgT[idx >> 5][idx & 31] = sgP[idx];
    }
  }
  float ssum[16];
#pragma unroll
  for (int i = 0; i < 16; ++i) ssum[i] = 0.f;
  __syncthreads();

  for (int ph = 0; ph < 4; ++ph) {
    int gg = gbase + ph * 64 + p64;
    int arow = wv * 16 + l15;
    int pixG = gbase + ph * 64 + arow;

    FU4 a0, a1;
    a0.v = xub4[pixG * 8 + l4];
    a1.v = xub4[pixG * 8 + 4 + l4];
#pragma unroll
    for (int Nt = 0; Nt < 4; ++Nt) {
      f32x4 acc = (f32x4){0.f, 0.f, 0.f, 0.f};
      FU b0f, b1f;
      int brow = Nt * 16 + l15;
#pragma unroll
      for (int jj = 0; jj < 4; ++jj) {
        b0f.u[jj] = WeT[brow][l4 * 4 + jj];
        b1f.u[jj] = WeT[brow][16 + l4 * 4 + jj];
      }
      acc = __builtin_amdgcn_mfma_f32_16x16x32_bf16(a0.f, b0f.f, acc, 0, 0, 0);
      acc = __builtin_amdgcn_mfma_f32_16x16x32_bf16(a1.f, b1f.f, acc, 0, 0, 0);
#pragma unroll
      for (int r = 0; r < 4; ++r)
        xef[wv * 16 + l4 * 4 + r][Nt * 16 + l15] = acc[r];
    }
    __syncthreads();   // B

    float xo[16];
#pragma unroll
    for (int i = 0; i < 16; ++i) {
      xo[i] = xef[p64][q * 16 + i];
      ssum[i] += xo[i];
      xeb[(q * 16 + i) * PIX + gg] = f2bf(xo[i]);
    }
#pragma unroll
    for (int ii = 0; ii < 8; ++ii)
      xp[p64][q * 8 + ii] = pk2(xo[2 * ii], xo[2 * ii + 1]);
    __syncthreads();   // C

    FU c0, c1;
#pragma unroll
    for (int jj = 0; jj < 4; ++jj) {
      c0.u[jj] = xp[arow][l4 * 4 + jj];
      c1.u[jj] = xp[arow][16 + l4 * 4 + jj];
    }
#pragma unroll
    for (int Nt = 0; Nt < 2; ++Nt) {
      float bb = sgb1[Nt * 16 + l15];
      f32x4 acc = (f32x4){bb, bb, bb, bb};
      FU b0f, b1f;
      int brow = Nt * 16 + l15;
#pragma unroll
      for (int jj = 0; jj < 4; ++jj) {
        b0f.u[jj] = SgT[brow][l4 * 4 + jj];
        b1f.u[jj] = SgT[brow][16 + l4 * 4 + jj];
      }
      acc = __builtin_amdgcn_mfma_f32_16x16x32_bf16(c0.f, b0f.f, acc, 0, 0, 0);
      acc = __builtin_amdgcn_mfma_f32_16x16x32_bf16(c1.f, b1f.f, acc, 0, 0, 0);
#pragma unroll
      for (int r = 0; r < 4; ++r) {
        float v = acc[r];
        xef[wv * 16 + l4 * 4 + r][Nt * 16 + l15] = v * sigmoidf_(v);
      }
    }
    __syncthreads();   // D

#pragma unroll
    for (int i = 0; i < 8; ++i)
      g1[(q * 8 + i) * PIX + gg] = xef[p64][q * 8 + i];
    __syncthreads();   // E: protect xp/xef reuse next phase
  }

#pragma unroll
  for (int i = 0; i < 16; ++i) {
    float v = ssum[i];
    v += __shfl_xor(v, 1);
    v += __shfl_xor(v, 2);
    v += __shfl_xor(v, 4);
    v += __shfl_xor(v, 8);
    v += __shfl_xor(v, 16);
    v += __shfl_xor(v, 32);
    if (l == 0) part[blockIdx.x * 64 + q * 16 + i] = v;
  }
}

// ---------------- flux scan (T=24) + all per-(b,t,d) coefficients ----------------
__global__ void k_flux(float* __restrict__ ws, float* __restrict__ out,
                       const float* __restrict__ dt_seq,
                       const float* __restrict__ flux_re, const float* __restrict__ flux_im,
                       const float* __restrict__ lam_flux,
                       const float* __restrict__ bf_re, const float* __restrict__ bf_im,
                       const float* __restrict__ c_re, const float* __restrict__ c_im,
                       const float* __restrict__ g_w, const float* __restrict__ g_b,
                       const float* __restrict__ a_decay, const float* __restrict__ b_freq) {
  int tid = threadIdx.x;
  if (tid >= 64) return;
  int b = tid >> 5, e = tid & 31;
  float sp_lf = softplusf_(lam_flux[e]);
  float lr = -softplusf_(a_decay[e]);
  float li = b_freq[e];
  float den = lr * lr + li * li;
  float bfr = bf_re[e], bfi = bf_im[e];
  float cr = c_re[e], ci = c_im[e];
  float fr = flux_re[b * 32 + e], fi = flux_im[b * 32 + e];
  const float* part = ws + WS_PART;
  for (int t = 0; t < 24; ++t) {
    int n = b * 24 + t;
    float dt = dt_seq[n];
    float A = expf(-sp_lf * dt);
    float xmr = 0.f, xmi = 0.f;
#pragma unroll
    for (int j = 0; j < 16; ++j) {
      xmr += part[(n * 16 + j) * 64 + e];
      xmi += part[(n * 16 + j) * 64 + 32 + e];
    }
    xmr *= (1.f / 4096.f);
    xmi *= (1.f / 4096.f);
    float Xr = (bfr * xmr - bfi * xmi) * dt;
    float Xi = (bfr * xmi + bfi * xmr) * dt;
    fr = A * fr + Xr;
    fi = A * fi + Xi;
    ws[WS_GATE + n * 32 + e] = sigmoidf_(fr * g_w[e] + g_b[e]);
    ws[WS_SRCR + n * 32 + e] = fr * cr - fi * ci;
    ws[WS_SRCI + n * 32 + e] = fr * ci + fi * cr;
    float er = expf(lr * dt);
    float odr = er * cosf(li * dt);
    float odi = er * sinf(li * dt);
    ws[WS_ODR + n * 32 + e] = odr;
    ws[WS_ODI + n * 32 + e] = odi;
    float nr = odr - 1.f, ni = odi;
    ws[WS_OFR + n * 32 + e] = (nr * lr + ni * li) / den;
    ws[WS_OFI + n * 32 + e] = (ni * lr - nr * li) / den;
  }
  out[FLUX_RE + b * 32 + e] = fr;
  out[FLUX_IM + b * 32 + e] = fi;
}

// ---------------- gate v3: dw 3x3 (shuffle stencil) + sg3 + sigmoid -> spg planes ---------
__global__ void __launch_bounds__(256) k_gate(
    const float* __restrict__ g1, float* __restrict__ spgP,
    const float* __restrict__ dw, const float* __restrict__ w2,
    const float* __restrict__ b2) {
  __shared__ float g2s[128][33];
  int tid = threadIdx.x;
  int l = tid & 63;
  int wv = tid >> 6;
  int r = wv >> 1, h = wv & 1;
  int pixbase = blockIdx.x * 128;
  int n = pixbase >> 12;
  int y = ((pixbase & 4095) >> 6) + r;
  int g = pixbase + r * 64 + l;
  int rp = r * 64 + l;

#pragma unroll
  for (int c = 0; c < 16; ++c) {
    int oc = h * 16 + c;
    const float* src = g1 + oc * PIX + n * 4096;
    const float* w = dw + oc * 9;        // uniform -> s_load
    float r0 = (y > 0)  ? src[(y - 1) * 64 + l] : 0.f;
    float r1 = src[y * 64 + l];
    float r2 = (y < 63) ? src[(y + 1) * 64 + l] : 0.f;
    float l0 = __shfl_up(r0, 1), t0 = __shfl_down(r0, 1);
    float l1 = __shfl_up(r1, 1), t1 = __shfl_down(r1, 1);
    float l2 = __shfl_up(r2, 1), t2 = __shfl_down(r2, 1);
    if (l == 0)  { l0 = 0.f; l1 = 0.f; l2 = 0.f; }
    if (l == 63) { t0 = 0.f; t1 = 0.f; t2 = 0.f; }
    float acc = 0.f;
    acc = fmaf(l0, w[0], acc); acc = fmaf(r0, w[1], acc); acc = fmaf(t0, w[2], acc);
    acc = fmaf(l1, w[3], acc); acc = fmaf(r1, w[4], acc); acc = fmaf(t1, w[5], acc);
    acc = fmaf(l2, w[6], acc); acc = fmaf(r2, w[7], acc); acc = fmaf(t2, w[8], acc);
    g2s[rp][oc] = acc;
  }
  __syncthreads();
  float g2a[32];
#pragma unroll
  for (int c = 0; c < 32; ++c) g2a[c] = g2s[rp][c];

#pragma unroll
  for (int c = 0; c < 16; ++c) {
    int e = h * 16 + c;
    float acc = b2[e];
#pragma unroll
    for (int k = 0; k < 32; ++k)
      acc = fmaf(g2a[k], w2[e * 32 + k], acc);     // uniform -> s_load
    spgP[e * PIX + g] = sigmoidf_(acc);
  }
}

// ---------------- fused forcing + temporal scan over T=24 (bf16 planes), emit h_out -------
__global__ void __launch_bounds__(256) k_scan(
    unsigned short* __restrict__ ub, const float* __restrict__ spgP,
    const float* __restrict__ gate, const float* __restrict__ srcr,
    const float* __restrict__ srci, const float* __restrict__ ofr_p,
    const float* __restrict__ ofi_p, const float* __restrict__ odr_p,
    const float* __restrict__ odi_p,
    const float* __restrict__ hre, const float* __restrict__ him,
    float* __restrict__ out) {
  int p = blockIdx.x * 256 + threadIdx.x;   // 0..4095
  int e = blockIdx.y;                        // 0..31 (block-uniform)
  int b = blockIdx.z;                        // 0..1
  float ur = 0.f, ui = 0.f;
  for (int t = 0; t < 24; ++t) {
    int n = b * 24 + t;
    int ie = n * 32 + e;
    int idx  = e * PIX + n * 4096 + p;
    int idxi = (32 + e) * PIX + n * 4096 + p;
    float gc = gate[ie] * spgP[idx];
    float xr = bf2f(ub[idx]), xi = bf2f(ub[idxi]);
    float om = 1.f - gc;
    float fr2 = xr * gc + srcr[ie] * om;
    float fi2 = xi * gc + srci[ie] * om;
    float ofr = ofr_p[ie], ofi = ofi_p[ie];
    float utr = fr2 * ofr - fi2 * ofi;
    float uti = fr2 * ofi + fi2 * ofr;
    if (t == 0) {
      int hb = (b * 4096 + p) * 32 + e;
      float hr = hre[hb], hi = him[hb];
      float odr0 = odr_p[ie], odi0 = odi_p[ie];
      utr += hr * odr0 - hi * odi0;
      uti += hr * odi0 + hi * odr0;
    }
    float ar = odr_p[ie], ai = odi_p[ie];
    float nr = ar * ur - ai * ui + utr;
    float ni = ar * ui + ai * ur + uti;
    ur = nr; ui = ni;
    ub[idx] = f2bf(ur);
    ub[idxi] = f2bf(ui);
  }
  out[HOUT_RE + (b * 4096 + p) * 32 + e] = ur;
  out[HOUT_IM + (b * 4096 + p) * 32 + e] = ui;
}

// ---------------- dec(Winv MFMA) + LN_t + FFN MFMA + z = xupd + dec + delta ---------------
__global__ void __launch_bounds__(256) k_final(
    const unsigned short* __restrict__ ub, const unsigned* __restrict__ xub,
    float* __restrict__ out, const unsigned* __restrict__ wibP,
    const float* __restrict__ lg, const float* __restrict__ lb,
    const float* __restrict__ w1, const float* __restrict__ b1,
    const float* __restrict__ w2, const float* __restrict__ b2) {
  __shared__ unsigned wiT[64][35];
  __shared__ unsigned w1T[128][35];
  __shared__ unsigned w2T[64][67];
  __shared__ unsigned dnp[64][35];
  __shared__ unsigned ho[64][67];
  __shared__ float ps1[64][5];
  __shared__ float ps2[64][5];

  int tid = threadIdx.x;
  int gbase = blockIdx.x * 256;
  int l = tid & 63, wv = tid >> 6;
  int l15 = l & 15, l4 = l >> 4;
  int p64 = l, q = wv;
  const uint4* xub4 = (const uint4*)xub;

  {
#pragma unroll
    for (int i = 0; i < 8; ++i) {
      int idx = tid + i * 256;
      wiT[idx >> 5][idx & 31] = wibP[idx];
    }
    int hid = tid & 127, half = tid >> 7;
#pragma unroll
    for (int i = 0; i < 16; ++i) {
      int cp = half * 16 + i;
      w1T[hid][cp] = pk2(w1[(2 * cp) * 128 + hid], w1[(2 * cp + 1) * 128 + hid]);
    }
#pragma unroll
    for (int i = 0; i < 16; ++i) {
      int hp = wv * 16 + i;
      w2T[l][hp] = pk2(w2[(2 * hp) * 64 + l], w2[(2 * hp + 1) * 64 + l]);
    }
  }
  float bb1v[8], bb2v[4];
#pragma unroll
  for (int Hn = 0; Hn < 8; ++Hn) bb1v[Hn] = b1[Hn * 16 + l15];
#pragma unroll
  for (int On = 0; On < 4; ++On) bb2v[On] = b2[On * 16 + l15];

  unsigned uvp[8];
  FU4 xa, xb;
  {
    int gg = gbase + p64;
#pragma unroll
    for (int ii = 0; ii < 8; ++ii) {
      int c0 = q * 16 + 2 * ii;
      unsigned lo = ub[c0 * PIX + gg];
      unsigned hi = ub[(c0 + 1) * PIX + gg];
      uvp[ii] = lo | (hi << 16);
    }
    xa.v = xub4[gg * 8 + q * 2];
    xb.v = xub4[gg * 8 + q * 2 + 1];
  }
  __syncthreads();

  for (int ph = 0; ph < 4; ++ph) {
    int gg = gbase + ph * 64 + p64;
    int arow = wv * 16 + l15;

#pragma unroll
    for (int ii = 0; ii < 8; ++ii)
      dnp[p64][q * 8 + ii] = uvp[ii];
    if (ph < 3) {
      int gg2 = gg + 64;
#pragma unroll
      for (int ii = 0; ii < 8; ++ii) {
        int c0 = q * 16 + 2 * ii;
        unsigned lo = ub[c0 * PIX + gg2];
        unsigned hi = ub[(c0 + 1) * PIX + gg2];
        uvp[ii] = lo | (hi << 16);
      }
    }
    __syncthreads();   // A

    {
      FU a0, a1;
#pragma unroll
      for (int jj = 0; jj < 4; ++jj) {
        a0.u[jj] = dnp[arow][l4 * 4 + jj];
        a1.u[jj] = dnp[arow][16 + l4 * 4 + jj];
      }
      float (*decf)[67] = (float(*)[67])ho;
#pragma unroll
      for (int Nt = 0; Nt < 4; ++Nt) {
        f32x4 acc = (f32x4){0.f, 0.f, 0.f, 0.f};
        FU b0f, b1f;
        int brow = Nt * 16 + l15;
#pragma unroll
        for (int jj = 0; jj < 4; ++jj) {
          b0f.u[jj] = wiT[brow][l4 * 4 + jj];
          b1f.u[jj] = wiT[brow][16 + l4 * 4 + jj];
        }
        acc = __builtin_amdgcn_mfma_f32_16x16x32_bf16(a0.f, b0f.f, acc, 0, 0, 0);
        acc = __builtin_amdgcn_mfma_f32_16x16x32_bf16(a1.f, b1f.f, acc, 0, 0, 0);
#pragma unroll
        for (int r = 0; r < 4; ++r)
          decf[wv * 16 + l4 * 4 + r][Nt * 16 + l15] = acc[r];
      }
    }
    __syncthreads();   // B

    float dv[16];
    float s1 = 0.f, s2 = 0.f;
    {
      float (*decf)[67] = (float(*)[67])ho;
#pragma unroll
      for (int i = 0; i < 16; ++i) {
        dv[i] = decf[p64][q * 16 + i];
        s1 += dv[i];
        s2 += dv[i] * dv[i];
      }
    }
    ps1[p64][q] = s1;
    ps2[p64][q] = s2;
    __syncthreads();   // C
    float m  = (ps1[p64][0] + ps1[p64][1] + ps1[p64][2] + ps1[p64][3]) * (1.f / 64.f);
    float e2 = (ps2[p64][0] + ps2[p64][1] + ps2[p64][2] + ps2[p64][3]) * (1.f / 64.f);
    float rs = rsqrtf(e2 - m * m + 1e-5f);
#pragma unroll
    for (int ii = 0; ii < 8; ++ii) {
      int c0 = q * 16 + 2 * ii;
      float a = (dv[2 * ii]     - m) * rs * lg[c0]     + lb[c0];
      float bvl = (dv[2 * ii + 1] - m) * rs * lg[c0 + 1] + lb[c0 + 1];
      dnp[p64][q * 8 + ii] = pk2(a, bvl);
    }
    __syncthreads();   // D

    FU a0, a1;
#pragma unroll
    for (int jj = 0; jj < 4; ++jj) {
      a0.u[jj] = dnp[arow][l4 * 4 + jj];
      a1.u[jj] = dnp[arow][16 + l4 * 4 + jj];
    }
    f32x4 acc[8];
#pragma unroll
    for (int Hn = 0; Hn < 8; ++Hn) {
      float bb = bb1v[Hn];
      acc[Hn] = (f32x4){bb, bb, bb, bb};
      FU b0f, b1f;
      int brow = Hn * 16 + l15;
#pragma unroll
      for (int jj = 0; jj < 4; ++jj) {
        b0f.u[jj] = w1T[brow][l4 * 4 + jj];
        b1f.u[jj] = w1T[brow][16 + l4 * 4 + jj];
      }
      acc[Hn] = __builtin_amdgcn_mfma_f32_16x16x32_bf16(a0.f, b0f.f, acc[Hn], 0, 0, 0);
      acc[Hn] = __builtin_amdgcn_mfma_f32_16x16x32_bf16(a1.f, b1f.f, acc[Hn], 0, 0, 0);
    }
    unsigned short (*hidb)[134] = (unsigned short(*)[134])ho;
#pragma unroll
    for (int Hn = 0; Hn < 8; ++Hn) {
#pragma unroll
      for (int r = 0; r < 4; ++r) {
        float v = acc[Hn][r];
        v = v * sigmoidf_(v);
        hidb[wv * 16 + l4 * 4 + r][Hn * 16 + l15] = f2bf(v);
      }
    }
    __syncthreads();   // E: TBAA fence (ushort stores -> u32 loads)

    FU a2[4];
#pragma unroll
    for (int kk = 0; kk < 4; ++kk)
#pragma unroll
      for (int jj = 0; jj < 4; ++jj)
        a2[kk].u[jj] = ((unsigned(*)[67])ho)[arow][kk * 16 + l4 * 4 + jj];
    f32x4 acc2[4];
#pragma unroll
    for (int On = 0; On < 4; ++On) {
      float bb = bb2v[On];
      acc2[On] = (f32x4){bb, bb, bb, bb};
#pragma unroll
      for (int kk = 0; kk < 4; ++kk) {
        FU b2f;
#pragma unroll
        for (int jj = 0; jj < 4; ++jj)
          b2f.u[jj] = w2T[On * 16 + l15][kk * 16 + l4 * 4 + jj];
        acc2[On] = __builtin_amdgcn_mfma_f32_16x16x32_bf16(a2[kk].f, b2f.f, acc2[On], 0, 0, 0);
      }
    }
    float (*o2f)[67] = (float(*)[67])ho;
#pragma unroll
    for (int On = 0; On < 4; ++On)
#pragma unroll
      for (int r = 0; r < 4; ++r)
        o2f[wv * 16 + l4 * 4 + r][On * 16 + l15] = acc2[On][r];
    __syncthreads();   // F

    {
      int nn = gg >> 12, pim = gg & 4095;
#pragma unroll
      for (int ii = 0; ii < 8; ++ii) {
        unsigned w = (ii < 4) ? xa.u[ii] : xb.u[ii - 4];
        float x0 = __uint_as_float(w << 16);
        float x1 = __uint_as_float(w & 0xFFFF0000u);
        int c0 = q * 16 + 2 * ii;
#pragma unroll
        for (int h = 0; h < 2; ++h) {
          int c = c0 + h;
          float xv = (h == 0) ? x0 : x1;
          float val = xv + o2f[p64][c] + dv[2 * ii + h];
          int d = c & 31;
          long off = ((c < 32) ? (long)MAIN_RE : (long)MAIN_IM) + (long)(nn * 32 + d) * 4096 + pim;
          out[off] = val;
        }
      }
      if (ph < 3) {
        int gg2 = gg + 64;
        xa.v = xub4[gg2 * 8 + q * 2];
        xb.v = xub4[gg2 * 8 + q * 2 + 1];
      }
    }
    __syncthreads();   // G: protect ho (o2f) reads vs next-phase dnp/decf writes
  }
}

extern "C" void kernel_launch(void* const* d_in, const int* in_sizes, int n_in,
                              void* d_out, int out_size, void* d_ws, size_t ws_size,
                              hipStream_t stream) {
  (void)in_sizes; (void)n_in; (void)out_size; (void)ws_size;
  const float* xre      = (const float*)d_in[0];
  const float* xim      = (const float*)d_in[1];
  const float* hre      = (const float*)d_in[2];
  const float* him      = (const float*)d_in[3];
  const float* flux_re  = (const float*)d_in[4];
  const float* flux_im  = (const float*)d_in[5];
  const float* dt_seq   = (const float*)d_in[6];
  const float* ln_s_g   = (const float*)d_in[7];
  const float* ln_s_b   = (const float*)d_in[8];
  const float* conv_w   = (const float*)d_in[9];
  const float* conv_b   = (const float*)d_in[10];
  const float* ln_t_g   = (const float*)d_in[11];
  const float* ln_t_b   = (const float*)d_in[12];
  const float* W_re     = (const float*)d_in[13];
  const float* W_im     = (const float*)d_in[14];
  const float* lam_flux = (const float*)d_in[15];
  const float* bf_re    = (const float*)d_in[16];
  const float* bf_im    = (const float*)d_in[17];
  const float* c_re     = (const float*)d_in[18];
  const float* c_im     = (const float*)d_in[19];
  const float* g_w      = (const float*)d_in[20];
  const float* g_b      = (const float*)d_in[21];
  const float* a_decay  = (const float*)d_in[22];
  const float* b_freq   = (const float*)d_in[23];
  const float* ffn_w1   = (const float*)d_in[24];
  const float* ffn_b1   = (const float*)d_in[25];
  const float* ffn_w2   = (const float*)d_in[26];
  const float* ffn_b2   = (const float*)d_in[27];
  const float* sg_w1    = (const float*)d_in[28];
  const float* sg_b1    = (const float*)d_in[29];
  const float* sg_dw    = (const float*)d_in[30];
  const float* sg_w2    = (const float*)d_in[31];
  const float* sg_b2    = (const float*)d_in[32];
  float* out = (float*)d_out;
  float* ws  = (float*)d_ws;

  unsigned* xub = (unsigned*)(ws + WS_XU);
  unsigned short* xeb = (unsigned short*)(ws + WS_XE);

  k_prep<<<789, 256, 0, stream>>>(xre, xim, ln_s_g, ln_s_b, W_re, W_im,
                                  conv_w, sg_w1, ws);
  k_conv<<<768, 256, 0, stream>>>((const unsigned*)(ws + WS_XN),
                                  (const unsigned short*)(ws + WS_WPK),
                                  conv_b, xre, xim, xub);
  k_xeig<<<768, 256, 0, stream>>>(xub, (const unsigned*)(ws + WS_WE),
                                  (const unsigned*)(ws + WS_SG),
                                  xeb, ws + WS_G1, sg_b1, ws + WS_PART);
  k_flux<<<1, 64, 0, stream>>>(ws, out, dt_seq, flux_re, flux_im, lam_flux,
                               bf_re, bf_im, c_re, c_im, g_w, g_b, a_decay, b_freq);
  k_gate<<<PIX / 128, 256, 0, stream>>>(ws + WS_G1, ws + WS_G2, sg_dw, sg_w2, sg_b2);
  k_scan<<<dim3(4096 / 256, 32, 2), 256, 0, stream>>>(xeb, ws + WS_G2,
                                                      ws + WS_GATE, ws + WS_SRCR, ws + WS_SRCI,
                                                      ws + WS_OFR, ws + WS_OFI,
                                                      ws + WS_ODR, ws + WS_ODI,
                                                      hre, him, out);
  k_final<<<768, 256, 0, stream>>>(xeb, xub, out, (const unsigned*)(ws + WS_WIB),
                                   ln_t_g, ln_t_b, ffn_w1, ffn_b1, ffn_w2, ffn_b2);
}

// Round 18
// 238.852 us; speedup vs baseline: 1.5626x; 1.2275x over previous
//
#include <hip/hip_runtime.h>
#include <math.h>

#define BB 2
#define TT 24
#define DD 32
#define HWp 4096            // 64*64
#define NN (BB*TT)          // 48
#define PIX (NN*HWp)        // 196608
#define C2 (2*DD)           // 64

// d_out offsets (floats)
#define MAIN_RE 0
#define MAIN_IM (NN*DD*HWp)              // 6291456
#define HOUT_RE (2*NN*DD*HWp)            // 12582912
#define HOUT_IM (HOUT_RE + BB*HWp*DD)    // 12845056
#define FLUX_RE (HOUT_RE + 2*BB*HWp*DD)  // 13107200
#define FLUX_IM (FLUX_RE + BB*DD)        // 13107264

// ws offsets (floats)
#define WS_XN   0                        // PIX*32: xnb bf16 channels-last (conv input)
#define WS_XU   (WS_XN + PIX*32)         // PIX*32: xupd bf16 channels-last (u32 pairs)
#define WS_XE   (WS_XU + PIX*32)         // PIX*32 used: xe/u bf16 planes (ushort)
#define WS_G1   (WS_XE + PIX*C2)         // PIX*32  g1 planes f32
#define WS_G2   (WS_G1 + PIX*DD)         // PIX*32  spg planes f32
#define WS_WINV (WS_G2 + PIX*DD)         // 2048 f32 (unused)
#define WS_SUMS (WS_WINV + 2048)         // 3072 (unused)
#define WS_GATE (WS_SUMS + 3072)         // 1536
#define WS_SRCR (WS_GATE + 1536)
#define WS_SRCI (WS_SRCR + 1536)
#define WS_ODR  (WS_SRCI + 1536)
#define WS_ODI  (WS_ODR + 1536)
#define WS_OFR  (WS_ODI + 1536)
#define WS_OFI  (WS_OFR + 1536)
#define WS_WPK  (WS_OFI + 1536)          // 36864 ushorts = 18432 floats
#define WS_PART (WS_WPK + 18432)         // 48*16*64 floats
#define WS_WE   (WS_PART + 49152)        // 2048 u32 eig weights [64][32]
#define WS_SG   (WS_WE + 2048)           // 1024 u32 sg1 weights [32][32]
#define WS_WIB  (WS_SG + 1024)           // 2048 u32 Winv packed [64][32]

typedef __attribute__((ext_vector_type(8))) short bf16x8;
typedef __attribute__((ext_vector_type(4))) float f32x4;
union FU { unsigned u[4]; bf16x8 f; };
union FU4 { uint4 v; unsigned u[4]; bf16x8 f; };

__device__ __forceinline__ float sigmoidf_(float x) { return 1.f / (1.f + expf(-x)); }
__device__ __forceinline__ float softplusf_(float x) { return log1pf(expf(x)); }
__device__ __forceinline__ unsigned short f2bf(float f) {
  unsigned u = __float_as_uint(f);
  return (unsigned short)((u + 0x7FFFu + ((u >> 16) & 1u)) >> 16);   // RNE
}
__device__ __forceinline__ unsigned pk2(float lo, float hi) {
  return (unsigned)f2bf(lo) | ((unsigned)f2bf(hi) << 16);
}
__device__ __forceinline__ float bf2f(unsigned short u) {
  return __uint_as_float((unsigned)u << 16);
}

// ---------------- fused prep: LN (0..767) || wprep (768..783) || eprep (784..787) ---------
__global__ void __launch_bounds__(256) k_prep(
    const float* __restrict__ xre, const float* __restrict__ xim,
    const float* __restrict__ g, const float* __restrict__ b,
    const float* __restrict__ Wre, const float* __restrict__ Wim,
    const float* __restrict__ conv_w, const float* __restrict__ sgw1,
    float* __restrict__ ws) {
  int bid = blockIdx.x;
  int tid = threadIdx.x;

  if (bid < 768) {
    int gid = bid * 256 + tid;
    int n = gid >> 12, p = gid & 4095;
    float v[64];
    float s = 0.f;
#pragma unroll
    for (int c = 0; c < 32; ++c) { v[c] = xre[(n * 32 + c) * 4096 + p]; s += v[c]; }
#pragma unroll
    for (int c = 0; c < 32; ++c) { v[32 + c] = xim[(n * 32 + c) * 4096 + p]; s += v[32 + c]; }
    float m = s * (1.f / 64.f);
    float vs = 0.f;
#pragma unroll
    for (int c = 0; c < 64; ++c) { float d = v[c] - m; vs += d * d; }
    float rs = rsqrtf(vs * (1.f / 64.f) + 1e-5f);
#pragma unroll
    for (int c = 0; c < 64; ++c) v[c] = (v[c] - m) * rs * g[c] + b[c];
    uint4* dst = (uint4*)ws + gid * 8;
#pragma unroll
    for (int q = 0; q < 8; ++q) {
      uint4 u;
      u.x = pk2(v[q * 8 + 0], v[q * 8 + 1]);
      u.y = pk2(v[q * 8 + 2], v[q * 8 + 3]);
      u.z = pk2(v[q * 8 + 4], v[q * 8 + 5]);
      u.w = pk2(v[q * 8 + 6], v[q * 8 + 7]);
      dst[q] = u;
    }
    return;
  }

  if (bid <= 783) {
    // conv weight pack slice: wpk[tap][oc][ci] bf16
    int slice = bid - 768;   // 0..15
    unsigned short* wpk = (unsigned short*)(ws + WS_WPK);
#pragma unroll
    for (int i = 0; i < 9; ++i) {
      int idx = slice * 2304 + i * 256 + tid;
      int tap = idx >> 12;
      int rem = idx & 4095;
      int oc = rem >> 6, ci = rem & 63;
      wpk[idx] = f2bf(conv_w[(oc * 64 + ci) * 9 + tap]);
    }
    return;
  }

  // eig + sg1 weight pack (blocks 784..787)
  {
    int t = (bid - 784) * 256 + tid;   // 0..1023
    unsigned* we = (unsigned*)(ws + WS_WE);
    unsigned* sg = (unsigned*)(ws + WS_SG);
    {
      int oc = t >> 5, kp = t & 31;
      sg[t] = pk2(sgw1[oc * 64 + 2 * kp], sgw1[oc * 64 + 2 * kp + 1]);
    }
#pragma unroll
    for (int h2 = 0; h2 < 2; ++h2) {
      int idx = t + h2 * 1024;
      int j = idx >> 5, kp = idx & 31;
      float v[2];
#pragma unroll
      for (int h = 0; h < 2; ++h) {
        int k = 2 * kp + h;
        float x;
        if (j < 32) x = (k < 32) ? Wre[k * 32 + j] : -Wim[(k - 32) * 32 + j];
        else        x = (k < 32) ? Wim[k * 32 + (j - 32)] : Wre[(k - 32) * 32 + (j - 32)];
        v[h] = x;
      }
      we[idx] = pk2(v[0], v[1]);
    }
  }
}

// ---------------- conv (blocks 1..768) || Winv Gauss-Jordan (block 0, 3-barrier) ----------
__global__ void __launch_bounds__(256) k_conv(
    const unsigned* __restrict__ xnb_u, const unsigned short* __restrict__ wpk,
    const float* __restrict__ bconv,
    const float* __restrict__ xre, const float* __restrict__ xim,
    unsigned* __restrict__ xub,
    const float* __restrict__ Wre, const float* __restrict__ Wim,
    unsigned* __restrict__ wib) {
  __shared__ unsigned xls[6 * 66 * 36];   // conv tiles / invert scratch / xsb out
  __shared__ int piv_s;
  __shared__ float prs[2];
  int bid = blockIdx.x;
  int tid = threadIdx.x;

  if (bid == 0) {
    // ---- 32x32 complex Gauss-Jordan, LDS carved from xls (float view) ----
    float* Mre = (float*)xls;            // [32][64]
    float* Mim = (float*)xls + 2048;     // [32][64]
    float* fre = (float*)xls + 4096;     // [32]
    float* fim = (float*)xls + 4128;     // [32]
    for (int idx = tid; idx < 2048; idx += 256) {
      int i = idx >> 6, j = idx & 63;
      if (j < 32) { Mre[idx] = Wre[i * 32 + j]; Mim[idx] = Wim[i * 32 + j]; }
      else        { Mre[idx] = (j - 32 == i) ? 1.f : 0.f; Mim[idx] = 0.f; }
    }
    __syncthreads();
    for (int k = 0; k < 32; ++k) {
      // P1: wave-parallel argmax + pivot value broadcast + reciprocal
      if (tid < 32) {
        int r = tid;
        float re = Mre[r * 64 + k], im = Mim[r * 64 + k];
        float mm = (r >= k) ? (fabsf(re) + fabsf(im)) : -1.f;
        int best = r;
#pragma unroll
        for (int off = 16; off > 0; off >>= 1) {
          float m2 = __shfl_xor(mm, off);
          int b2 = __shfl_xor(best, off);
          if (m2 > mm || (m2 == mm && b2 < best)) { mm = m2; best = b2; }
        }
        float pvr = __shfl(re, best);
        float pvi = __shfl(im, best);
        if (tid == 0) {
          float dd = pvr * pvr + pvi * pvi;
          piv_s = best;
          prs[0] = pvr / dd;
          prs[1] = -pvi / dd;
        }
      }
      __syncthreads();   // B1
      int pv = piv_s;
      float pr = prs[0], pi = prs[1];
      // P2: fused swap+scale (thread = column) + factor snapshot
      if (tid < 64) {
        int l = tid;
        float kr = Mre[k * 64 + l], ki = Mim[k * 64 + l];
        float vr = Mre[pv * 64 + l], vi = Mim[pv * 64 + l];
        Mre[pv * 64 + l] = kr; Mim[pv * 64 + l] = ki;
        Mre[k * 64 + l] = vr * pr - vi * pi;
        Mim[k * 64 + l] = vr * pi + vi * pr;
        if (l == k) { fre[pv] = kr; fim[pv] = ki; }        // fre[pv] = old M[k][k]
        if (l < 32 && l != pv && l != k) {                  // rows not in {k,pv}: untouched
          fre[l] = Mre[l * 64 + k];
          fim[l] = Mim[l * 64 + k];
        }
      }
      __syncthreads();   // B2
      // P3: elimination
      for (int idx = tid; idx < 2048; idx += 256) {
        int i = idx >> 6, j = idx & 63;
        if (i != k) {
          float fr = fre[i], fi2 = fim[i];
          float ar = Mre[k * 64 + j], ai = Mim[k * 64 + j];
          Mre[idx] -= fr * ar - fi2 * ai;
          Mim[idx] -= fr * ai + fi2 * ar;
        }
      }
      __syncthreads();   // B3
    }
    for (int idx = tid; idx < 2048; idx += 256) {
      int j = idx >> 5, kp = idx & 31;
      float v[2];
#pragma unroll
      for (int h = 0; h < 2; ++h) {
        int kk = 2 * kp + h;
        float x;
        if (j < 32) x = (kk < 32) ? Mre[kk * 64 + 32 + j] : -Mim[(kk - 32) * 64 + 32 + j];
        else        x = (kk < 32) ? Mim[kk * 64 + 32 + (j - 32)] : Mre[(kk - 32) * 64 + 32 + (j - 32)];
        v[h] = x;
      }
      wib[idx] = pk2(v[0], v[1]);
    }
    return;
  }

  // ---- conv body (blocks 1..768) ----
  int cb = bid - 1;
  int n = cb >> 4;
  int y0 = (cb & 15) * 4;
  int wv = tid >> 6, l = tid & 63;
  int l15 = l & 15, l4 = l >> 4;

  const uint4* xnb4 = (const uint4*)xnb_u;
  for (int idx = tid; idx < 396; idx += 256) {
    int r = idx / 66, c = idx - r * 66;
    int y = y0 - 1 + r, x = c - 1;
    bool valid = ((unsigned)y < 64u) & ((unsigned)x < 64u);
    int pg = n * 4096 + y * 64 + x;
    uint4 z; z.x = z.y = z.z = z.w = 0u;
#pragma unroll
    for (int q = 0; q < 8; ++q) {
      uint4 v = valid ? xnb4[pg * 8 + q] : z;
      *(uint4*)&xls[idx * 36 + q * 4] = v;
    }
  }
  __syncthreads();

  f32x4 acc[4][4];
#pragma unroll
  for (int Nt = 0; Nt < 4; ++Nt) {
    float bb = bconv[Nt * 16 + l15];
#pragma unroll
    for (int mt = 0; mt < 4; ++mt) acc[mt][Nt] = (f32x4){bb, bb, bb, bb};
  }

  const uint4* wq = (const uint4*)wpk;
#pragma unroll
  for (int tap = 0; tap < 9; ++tap) {
    int ky = tap / 3, kx = tap - ky * 3;
    int rowbase = (wv + ky) * 66 + kx + l15;
#pragma unroll
    for (int ks = 0; ks < 2; ++ks) {
      FU4 B[4];
#pragma unroll
      for (int Nt = 0; Nt < 4; ++Nt)
        B[Nt].v = wq[tap * 512 + (Nt * 16 + l15) * 8 + ks * 4 + l4];
#pragma unroll
      for (int mt = 0; mt < 4; ++mt) {
        FU4 A;
        A.v = *(const uint4*)&xls[(rowbase + mt * 16) * 36 + ks * 16 + l4 * 4];
#pragma unroll
        for (int Nt = 0; Nt < 4; ++Nt)
          acc[mt][Nt] = __builtin_amdgcn_mfma_f32_16x16x32_bf16(A.f, B[Nt].f, acc[mt][Nt], 0, 0, 0);
      }
    }
  }
  __syncthreads();   // xls input reads done; reuse as ushort xsb [256][66]

  unsigned short (*xsb)[66] = (unsigned short(*)[66])xls;
#pragma unroll
  for (int Nt = 0; Nt < 4; ++Nt) {
    int oc = Nt * 16 + l15;
    int d = oc & 31;
    const float* resid = (oc < 32) ? xre : xim;
    const float* rsd = resid + (n * 32 + d) * 4096;
#pragma unroll
    for (int mt = 0; mt < 4; ++mt) {
      int lp0 = wv * 64 + mt * 16 + l4 * 4;
      int pixbase = y0 * 64 + lp0;
#pragma unroll
      for (int r = 0; r < 4; ++r)
        xsb[lp0 + r][oc] = f2bf(rsd[pixbase + r] + acc[mt][Nt][r]);
    }
  }
  __syncthreads();   // TBAA fence: ushort stores -> u32 reads

  int pixG0 = n * 4096 + y0 * 64;
#pragma unroll
  for (int i = 0; i < 8; ++i) {
    int idx = tid + 256 * i;
    int lp = idx >> 3, q4 = idx & 7;
    uint4 v;
    v.x = xls[lp * 33 + q4 * 4 + 0];
    v.y = xls[lp * 33 + q4 * 4 + 1];
    v.z = xls[lp * 33 + q4 * 4 + 2];
    v.w = xls[lp * 33 + q4 * 4 + 3];
    ((uint4*)xub)[(pixG0 + lp) * 8 + q4] = v;
  }
}

// ---------------- x_eig v5: A-frags direct from global xub; xe -> bf16 planes -------------
__global__ void __launch_bounds__(256) k_xeig(
    const unsigned* __restrict__ xub, const unsigned* __restrict__ weP,
    const unsigned* __restrict__ sgP, unsigned short* __restrict__ xeb,
    float* __restrict__ g1, const float* __restrict__ sgb1,
    float* __restrict__ part) {
  __shared__ unsigned WeT[64][35];
  __shared__ unsigned SgT[32][35];
  __shared__ unsigned xp[64][35];
  __shared__ float xef[64][67];

  int tid = threadIdx.x;
  int gbase = blockIdx.x * 256;
  int l = tid & 63, wv = tid >> 6;
  int l15 = l & 15, l4 = l >> 4;
  int p64 = l, q = wv;
  const uint4* xub4 = (const uint4*)xub;

  {
#pragma unroll
    for (int i = 0; i < 8; ++i) {
      int idx = tid + i * 256;
      WeT[idx >> 5][idx & 31] = weP[idx];
    }
#pragma unroll
    for (int i = 0; i < 4; ++i) {
      int idx = tid + i * 256;
      SgT[idx >> 5][idx & 31] = sgP[idx];
    }
  }
  float ssum[16];
#pragma unroll
  for (int i = 0; i < 16; ++i) ssum[i] = 0.f;
  __syncthreads();

  for (int ph = 0; ph < 4; ++ph) {
    int gg = gbase + ph * 64 + p64;
    int arow = wv * 16 + l15;
    int pixG = gbase + ph * 64 + arow;

    FU4 a0, a1;
    a0.v = xub4[pixG * 8 + l4];
    a1.v = xub4[pixG * 8 + 4 + l4];
#pragma unroll
    for (int Nt = 0; Nt < 4; ++Nt) {
      f32x4 acc = (f32x4){0.f, 0.f, 0.f, 0.f};
      FU b0f, b1f;
      int brow = Nt * 16 + l15;
#pragma unroll
      for (int jj = 0; jj < 4; ++jj) {
        b0f.u[jj] = WeT[brow][l4 * 4 + jj];
        b1f.u[jj] = WeT[brow][16 + l4 * 4 + jj];
      }
      acc = __builtin_amdgcn_mfma_f32_16x16x32_bf16(a0.f, b0f.f, acc, 0, 0, 0);
      acc = __builtin_amdgcn_mfma_f32_16x16x32_bf16(a1.f, b1f.f, acc, 0, 0, 0);
#pragma unroll
      for (int r = 0; r < 4; ++r)
        xef[wv * 16 + l4 * 4 + r][Nt * 16 + l15] = acc[r];
    }
    __syncthreads();   // B

    float xo[16];
#pragma unroll
    for (int i = 0; i < 16; ++i) {
      xo[i] = xef[p64][q * 16 + i];
      ssum[i] += xo[i];
      xeb[(q * 16 + i) * PIX + gg] = f2bf(xo[i]);
    }
#pragma unroll
    for (int ii = 0; ii < 8; ++ii)
      xp[p64][q * 8 + ii] = pk2(xo[2 * ii], xo[2 * ii + 1]);
    __syncthreads();   // C

    FU c0, c1;
#pragma unroll
    for (int jj = 0; jj < 4; ++jj) {
      c0.u[jj] = xp[arow][l4 * 4 + jj];
      c1.u[jj] = xp[arow][16 + l4 * 4 + jj];
    }
#pragma unroll
    for (int Nt = 0; Nt < 2; ++Nt) {
      float bb = sgb1[Nt * 16 + l15];
      f32x4 acc = (f32x4){bb, bb, bb, bb};
      FU b0f, b1f;
      int brow = Nt * 16 + l15;
#pragma unroll
      for (int jj = 0; jj < 4; ++jj) {
        b0f.u[jj] = SgT[brow][l4 * 4 + jj];
        b1f.u[jj] = SgT[brow][16 + l4 * 4 + jj];
      }
      acc = __builtin_amdgcn_mfma_f32_16x16x32_bf16(c0.f, b0f.f, acc, 0, 0, 0);
      acc = __builtin_amdgcn_mfma_f32_16x16x32_bf16(c1.f, b1f.f, acc, 0, 0, 0);
#pragma unroll
      for (int r = 0; r < 4; ++r) {
        float v = acc[r];
        xef[wv * 16 + l4 * 4 + r][Nt * 16 + l15] = v * sigmoidf_(v);
      }
    }
    __syncthreads();   // D

#pragma unroll
    for (int i = 0; i < 8; ++i)
      g1[(q * 8 + i) * PIX + gg] = xef[p64][q * 8 + i];
    __syncthreads();   // E: protect xp/xef reuse next phase
  }

#pragma unroll
  for (int i = 0; i < 16; ++i) {
    float v = ssum[i];
    v += __shfl_xor(v, 1);
    v += __shfl_xor(v, 2);
    v += __shfl_xor(v, 4);
    v += __shfl_xor(v, 8);
    v += __shfl_xor(v, 16);
    v += __shfl_xor(v, 32);
    if (l == 0) part[blockIdx.x * 64 + q * 16 + i] = v;
  }
}

// ---------------- flux scan (T=24) + all per-(b,t,d) coefficients ----------------
__global__ void k_flux(float* __restrict__ ws, float* __restrict__ out,
                       const float* __restrict__ dt_seq,
                       const float* __restrict__ flux_re, const float* __restrict__ flux_im,
                       const float* __restrict__ lam_flux,
                       const float* __restrict__ bf_re, const float* __restrict__ bf_im,
                       const float* __restrict__ c_re, const float* __restrict__ c_im,
                       const float* __restrict__ g_w, const float* __restrict__ g_b,
                       const float* __restrict__ a_decay, const float* __restrict__ b_freq) {
  int tid = threadIdx.x;
  if (tid >= 64) return;
  int b = tid >> 5, e = tid & 31;
  float sp_lf = softplusf_(lam_flux[e]);
  float lr = -softplusf_(a_decay[e]);
  float li = b_freq[e];
  float den = lr * lr + li * li;
  float bfr = bf_re[e], bfi = bf_im[e];
  float cr = c_re[e], ci = c_im[e];
  float fr = flux_re[b * 32 + e], fi = flux_im[b * 32 + e];
  const float* part = ws + WS_PART;
  for (int t = 0; t < 24; ++t) {
    int n = b * 24 + t;
    float dt = dt_seq[n];
    float A = expf(-sp_lf * dt);
    float xmr = 0.f, xmi = 0.f;
#pragma unroll
    for (int j = 0; j < 16; ++j) {
      xmr += part[(n * 16 + j) * 64 + e];
      xmi += part[(n * 16 + j) * 64 + 32 + e];
    }
    xmr *= (1.f / 4096.f);
    xmi *= (1.f / 4096.f);
    float Xr = (bfr * xmr - bfi * xmi) * dt;
    float Xi = (bfr * xmi + bfi * xmr) * dt;
    fr = A * fr + Xr;
    fi = A * fi + Xi;
    ws[WS_GATE + n * 32 + e] = sigmoidf_(fr * g_w[e] + g_b[e]);
    ws[WS_SRCR + n * 32 + e] = fr * cr - fi * ci;
    ws[WS_SRCI + n * 32 + e] = fr * ci + fi * cr;
    float er = expf(lr * dt);
    float odr = er * cosf(li * dt);
    float odi = er * sinf(li * dt);
    ws[WS_ODR + n * 32 + e] = odr;
    ws[WS_ODI + n * 32 + e] = odi;
    float nr = odr - 1.f, ni = odi;
    ws[WS_OFR + n * 32 + e] = (nr * lr + ni * li) / den;
    ws[WS_OFI + n * 32 + e] = (ni * lr - nr * li) / den;
  }
  out[FLUX_RE + b * 32 + e] = fr;
  out[FLUX_IM + b * 32 + e] = fi;
}

// ---------------- gate v3: dw 3x3 (shuffle stencil) + sg3 + sigmoid -> spg planes ---------
__global__ void __launch_bounds__(256) k_gate(
    const float* __restrict__ g1, float* __restrict__ spgP,
    const float* __restrict__ dw, const float* __restrict__ w2,
    const float* __restrict__ b2) {
  __shared__ float g2s[128][33];
  int tid = threadIdx.x;
  int l = tid & 63;
  int wv = tid >> 6;
  int r = wv >> 1, h = wv & 1;
  int pixbase = blockIdx.x * 128;
  int n = pixbase >> 12;
  int y = ((pixbase & 4095) >> 6) + r;
  int g = pixbase + r * 64 + l;
  int rp = r * 64 + l;

#pragma unroll
  for (int c = 0; c < 16; ++c) {
    int oc = h * 16 + c;
    const float* src = g1 + oc * PIX + n * 4096;
    const float* w = dw + oc * 9;        // uniform -> s_load
    float r0 = (y > 0)  ? src[(y - 1) * 64 + l] : 0.f;
    float r1 = src[y * 64 + l];
    float r2 = (y < 63) ? src[(y + 1) * 64 + l] : 0.f;
    float l0 = __shfl_up(r0, 1), t0 = __shfl_down(r0, 1);
    float l1 = __shfl_up(r1, 1), t1 = __shfl_down(r1, 1);
    float l2 = __shfl_up(r2, 1), t2 = __shfl_down(r2, 1);
    if (l == 0)  { l0 = 0.f; l1 = 0.f; l2 = 0.f; }
    if (l == 63) { t0 = 0.f; t1 = 0.f; t2 = 0.f; }
    float acc = 0.f;
    acc = fmaf(l0, w[0], acc); acc = fmaf(r0, w[1], acc); acc = fmaf(t0, w[2], acc);
    acc = fmaf(l1, w[3], acc); acc = fmaf(r1, w[4], acc); acc = fmaf(t1, w[5], acc);
    acc = fmaf(l2, w[6], acc); acc = fmaf(r2, w[7], acc); acc = fmaf(t2, w[8], acc);
    g2s[rp][oc] = acc;
  }
  __syncthreads();
  float g2a[32];
#pragma unroll
  for (int c = 0; c < 32; ++c) g2a[c] = g2s[rp][c];

#pragma unroll
  for (int c = 0; c < 16; ++c) {
    int e = h * 16 + c;
    float acc = b2[e];
#pragma unroll
    for (int k = 0; k < 32; ++k)
      acc = fmaf(g2a[k], w2[e * 32 + k], acc);     // uniform -> s_load
    spgP[e * PIX + g] = sigmoidf_(acc);
  }
}

// ---------------- fused forcing + temporal scan over T=24 (bf16 planes), emit h_out -------
__global__ void __launch_bounds__(256) k_scan(
    unsigned short* __restrict__ ub, const float* __restrict__ spgP,
    const float* __restrict__ gate, const float* __restrict__ srcr,
    const float* __restrict__ srci, const float* __restrict__ ofr_p,
    const float* __restrict__ ofi_p, const float* __restrict__ odr_p,
    const float* __restrict__ odi_p,
    const float* __restrict__ hre, const float* __restrict__ him,
    float* __restrict__ out) {
  int p = blockIdx.x * 256 + threadIdx.x;   // 0..4095
  int e = blockIdx.y;                        // 0..31 (block-uniform)
  int b = blockIdx.z;                        // 0..1
  float ur = 0.f, ui = 0.f;
  for (int t = 0; t < 24; ++t) {
    int n = b * 24 + t;
    int ie = n * 32 + e;
    int idx  = e * PIX + n * 4096 + p;
    int idxi = (32 + e) * PIX + n * 4096 + p;
    float gc = gate[ie] * spgP[idx];
    float xr = bf2f(ub[idx]), xi = bf2f(ub[idxi]);
    float om = 1.f - gc;
    float fr2 = xr * gc + srcr[ie] * om;
    float fi2 = xi * gc + srci[ie] * om;
    float ofr = ofr_p[ie], ofi = ofi_p[ie];
    float utr = fr2 * ofr - fi2 * ofi;
    float uti = fr2 * ofi + fi2 * ofr;
    if (t == 0) {
      int hb = (b * 4096 + p) * 32 + e;
      float hr = hre[hb], hi = him[hb];
      float odr0 = odr_p[ie], odi0 = odi_p[ie];
      utr += hr * odr0 - hi * odi0;
      uti += hr * odi0 + hi * odr0;
    }
    float ar = odr_p[ie], ai = odi_p[ie];
    float nr = ar * ur - ai * ui + utr;
    float ni = ar * ui + ai * ur + uti;
    ur = nr; ui = ni;
    ub[idx] = f2bf(ur);
    ub[idxi] = f2bf(ui);
  }
  out[HOUT_RE + (b * 4096 + p) * 32 + e] = ur;
  out[HOUT_IM + (b * 4096 + p) * 32 + e] = ui;
}

// ---------------- dec(Winv MFMA) + LN_t + FFN MFMA + z = xupd + dec + delta ---------------
__global__ void __launch_bounds__(256) k_final(
    const unsigned short* __restrict__ ub, const unsigned* __restrict__ xub,
    float* __restrict__ out, const unsigned* __restrict__ wibP,
    const float* __restrict__ lg, const float* __restrict__ lb,
    const float* __restrict__ w1, const float* __restrict__ b1,
    const float* __restrict__ w2, const float* __restrict__ b2) {
  __shared__ unsigned wiT[64][35];
  __shared__ unsigned w1T[128][35];
  __shared__ unsigned w2T[64][67];
  __shared__ unsigned dnp[64][35];
  __shared__ unsigned ho[64][67];
  __shared__ float ps1[64][5];
  __shared__ float ps2[64][5];

  int tid = threadIdx.x;
  int gbase = blockIdx.x * 256;
  int l = tid & 63, wv = tid >> 6;
  int l15 = l & 15, l4 = l >> 4;
  int p64 = l, q = wv;
  const uint4* xub4 = (const uint4*)xub;

  {
#pragma unroll
    for (int i = 0; i < 8; ++i) {
      int idx = tid + i * 256;
      wiT[idx >> 5][idx & 31] = wibP[idx];
    }
    int hid = tid & 127, half = tid >> 7;
#pragma unroll
    for (int i = 0; i < 16; ++i) {
      int cp = half * 16 + i;
      w1T[hid][cp] = pk2(w1[(2 * cp) * 128 + hid], w1[(2 * cp + 1) * 128 + hid]);
    }
#pragma unroll
    for (int i = 0; i < 16; ++i) {
      int hp = wv * 16 + i;
      w2T[l][hp] = pk2(w2[(2 * hp) * 64 + l], w2[(2 * hp + 1) * 64 + l]);
    }
  }
  float bb1v[8], bb2v[4];
#pragma unroll
  for (int Hn = 0; Hn < 8; ++Hn) bb1v[Hn] = b1[Hn * 16 + l15];
#pragma unroll
  for (int On = 0; On < 4; ++On) bb2v[On] = b2[On * 16 + l15];

  unsigned uvp[8];
  FU4 xa, xb;
  {
    int gg = gbase + p64;
#pragma unroll
    for (int ii = 0; ii < 8; ++ii) {
      int c0 = q * 16 + 2 * ii;
      unsigned lo = ub[c0 * PIX + gg];
      unsigned hi = ub[(c0 + 1) * PIX + gg];
      uvp[ii] = lo | (hi << 16);
    }
    xa.v = xub4[gg * 8 + q * 2];
    xb.v = xub4[gg * 8 + q * 2 + 1];
  }
  __syncthreads();

  for (int ph = 0; ph < 4; ++ph) {
    int gg = gbase + ph * 64 + p64;
    int arow = wv * 16 + l15;

#pragma unroll
    for (int ii = 0; ii < 8; ++ii)
      dnp[p64][q * 8 + ii] = uvp[ii];
    if (ph < 3) {
      int gg2 = gg + 64;
#pragma unroll
      for (int ii = 0; ii < 8; ++ii) {
        int c0 = q * 16 + 2 * ii;
        unsigned lo = ub[c0 * PIX + gg2];
        unsigned hi = ub[(c0 + 1) * PIX + gg2];
        uvp[ii] = lo | (hi << 16);
      }
    }
    __syncthreads();   // A

    {
      FU a0, a1;
#pragma unroll
      for (int jj = 0; jj < 4; ++jj) {
        a0.u[jj] = dnp[arow][l4 * 4 + jj];
        a1.u[jj] = dnp[arow][16 + l4 * 4 + jj];
      }
      float (*decf)[67] = (float(*)[67])ho;
#pragma unroll
      for (int Nt = 0; Nt < 4; ++Nt) {
        f32x4 acc = (f32x4){0.f, 0.f, 0.f, 0.f};
        FU b0f, b1f;
        int brow = Nt * 16 + l15;
#pragma unroll
        for (int jj = 0; jj < 4; ++jj) {
          b0f.u[jj] = wiT[brow][l4 * 4 + jj];
          b1f.u[jj] = wiT[brow][16 + l4 * 4 + jj];
        }
        acc = __builtin_amdgcn_mfma_f32_16x16x32_bf16(a0.f, b0f.f, acc, 0, 0, 0);
        acc = __builtin_amdgcn_mfma_f32_16x16x32_bf16(a1.f, b1f.f, acc, 0, 0, 0);
#pragma unroll
        for (int r = 0; r < 4; ++r)
          decf[wv * 16 + l4 * 4 + r][Nt * 16 + l15] = acc[r];
      }
    }
    __syncthreads();   // B

    float dv[16];
    float s1 = 0.f, s2 = 0.f;
    {
      float (*decf)[67] = (float(*)[67])ho;
#pragma unroll
      for (int i = 0; i < 16; ++i) {
        dv[i] = decf[p64][q * 16 + i];
        s1 += dv[i];
        s2 += dv[i] * dv[i];
      }
    }
    ps1[p64][q] = s1;
    ps2[p64][q] = s2;
    __syncthreads();   // C
    float m  = (ps1[p64][0] + ps1[p64][1] + ps1[p64][2] + ps1[p64][3]) * (1.f / 64.f);
    float e2 = (ps2[p64][0] + ps2[p64][1] + ps2[p64][2] + ps2[p64][3]) * (1.f / 64.f);
    float rs = rsqrtf(e2 - m * m + 1e-5f);
#pragma unroll
    for (int ii = 0; ii < 8; ++ii) {
      int c0 = q * 16 + 2 * ii;
      float a = (dv[2 * ii]     - m) * rs * lg[c0]     + lb[c0];
      float bvl = (dv[2 * ii + 1] - m) * rs * lg[c0 + 1] + lb[c0 + 1];
      dnp[p64][q * 8 + ii] = pk2(a, bvl);
    }
    __syncthreads();   // D

    FU a0, a1;
#pragma unroll
    for (int jj = 0; jj < 4; ++jj) {
      a0.u[jj] = dnp[arow][l4 * 4 + jj];
      a1.u[jj] = dnp[arow][16 + l4 * 4 + jj];
    }
    f32x4 acc[8];
#pragma unroll
    for (int Hn = 0; Hn < 8; ++Hn) {
      float bb = bb1v[Hn];
      acc[Hn] = (f32x4){bb, bb, bb, bb};
      FU b0f, b1f;
      int brow = Hn * 16 + l15;
#pragma unroll
      for (int jj = 0; jj < 4; ++jj) {
        b0f.u[jj] = w1T[brow][l4 * 4 + jj];
        b1f.u[jj] = w1T[brow][16 + l4 * 4 + jj];
      }
      acc[Hn] = __builtin_amdgcn_mfma_f32_16x16x32_bf16(a0.f, b0f.f, acc[Hn], 0, 0, 0);
      acc[Hn] = __builtin_amdgcn_mfma_f32_16x16x32_bf16(a1.f, b1f.f, acc[Hn], 0, 0, 0);
    }
    unsigned short (*hidb)[134] = (unsigned short(*)[134])ho;
#pragma unroll
    for (int Hn = 0; Hn < 8; ++Hn) {
#pragma unroll
      for (int r = 0; r < 4; ++r) {
        float v = acc[Hn][r];
        v = v * sigmoidf_(v);
        hidb[wv * 16 + l4 * 4 + r][Hn * 16 + l15] = f2bf(v);
      }
    }
    __syncthreads();   // E: TBAA fence (ushort stores -> u32 loads)

    FU a2[4];
#pragma unroll
    for (int kk = 0; kk < 4; ++kk)
#pragma unroll
      for (int jj = 0; jj < 4; ++jj)
        a2[kk].u[jj] = ((unsigned(*)[67])ho)[arow][kk * 16 + l4 * 4 + jj];
    f32x4 acc2[4];
#pragma unroll
    for (int On = 0; On < 4; ++On) {
      float bb = bb2v[On];
      acc2[On] = (f32x4){bb, bb, bb, bb};
#pragma unroll
      for (int kk = 0; kk < 4; ++kk) {
        FU b2f;
#pragma unroll
        for (int jj = 0; jj < 4; ++jj)
          b2f.u[jj] = w2T[On * 16 + l15][kk * 16 + l4 * 4 + jj];
        acc2[On] = __builtin_amdgcn_mfma_f32_16x16x32_bf16(a2[kk].f, b2f.f, acc2[On], 0, 0, 0);
      }
    }
    float (*o2f)[67] = (float(*)[67])ho;
#pragma unroll
    for (int On = 0; On < 4; ++On)
#pragma unroll
      for (int r = 0; r < 4; ++r)
        o2f[wv * 16 + l4 * 4 + r][On * 16 + l15] = acc2[On][r];
    __syncthreads();   // F

    {
      int nn = gg >> 12, pim = gg & 4095;
#pragma unroll
      for (int ii = 0; ii < 8; ++ii) {
        unsigned w = (ii < 4) ? xa.u[ii] : xb.u[ii - 4];
        float x0 = __uint_as_float(w << 16);
        float x1 = __uint_as_float(w & 0xFFFF0000u);
        int c0 = q * 16 + 2 * ii;
#pragma unroll
        for (int h = 0; h < 2; ++h) {
          int c = c0 + h;
          float xv = (h == 0) ? x0 : x1;
          float val = xv + o2f[p64][c] + dv[2 * ii + h];
          int d = c & 31;
          long off = ((c < 32) ? (long)MAIN_RE : (long)MAIN_IM) + (long)(nn * 32 + d) * 4096 + pim;
          out[off] = val;
        }
      }
      if (ph < 3) {
        int gg2 = gg + 64;
        xa.v = xub4[gg2 * 8 + q * 2];
        xb.v = xub4[gg2 * 8 + q * 2 + 1];
      }
    }
    __syncthreads();   // G: protect ho (o2f) reads vs next-phase dnp/decf writes
  }
}

extern "C" void kernel_launch(void* const* d_in, const int* in_sizes, int n_in,
                              void* d_out, int out_size, void* d_ws, size_t ws_size,
                              hipStream_t stream) {
  (void)in_sizes; (void)n_in; (void)out_size; (void)ws_size;
  const float* xre      = (const float*)d_in[0];
  const float* xim      = (const float*)d_in[1];
  const float* hre      = (const float*)d_in[2];
  const float* him      = (const float*)d_in[3];
  const float* flux_re  = (const float*)d_in[4];
  const float* flux_im  = (const float*)d_in[5];
  const float* dt_seq   = (const float*)d_in[6];
  const float* ln_s_g   = (const float*)d_in[7];
  const float* ln_s_b   = (const float*)d_in[8];
  const float* conv_w   = (const float*)d_in[9];
  const float* conv_b   = (const float*)d_in[10];
  const float* ln_t_g   = (const float*)d_in[11];
  const float* ln_t_b   = (const float*)d_in[12];
  const float* W_re     = (const float*)d_in[13];
  const float* W_im     = (const float*)d_in[14];
  const float* lam_flux = (const float*)d_in[15];
  const float* bf_re    = (const float*)d_in[16];
  const float* bf_im    = (const float*)d_in[17];
  const float* c_re     = (const float*)d_in[18];
  const float* c_im     = (const float*)d_in[19];
  const float* g_w      = (const float*)d_in[20];
  const float* g_b      = (const float*)d_in[21];
  const float* a_decay  = (const float*)d_in[22];
  const float* b_freq   = (const float*)d_in[23];
  const float* ffn_w1   = (const float*)d_in[24];
  const float* ffn_b1   = (const float*)d_in[25];
  const float* ffn_w2   = (const float*)d_in[26];
  const float* ffn_b2   = (const float*)d_in[27];
  const float* sg_w1    = (const float*)d_in[28];
  const float* sg_b1    = (const float*)d_in[29];
  const float* sg_dw    = (const float*)d_in[30];
  const float* sg_w2    = (const float*)d_in[31];
  const float* sg_b2    = (const float*)d_in[32];
  float* out = (float*)d_out;
  float* ws  = (float*)d_ws;

  unsigned* xub = (unsigned*)(ws + WS_XU);
  unsigned short* xeb = (unsigned short*)(ws + WS_XE);

  k_prep<<<788, 256, 0, stream>>>(xre, xim, ln_s_g, ln_s_b, W_re, W_im,
                                  conv_w, sg_w1, ws);
  k_conv<<<769, 256, 0, stream>>>((const unsigned*)(ws + WS_XN),
                                  (const unsigned short*)(ws + WS_WPK),
                                  conv_b, xre, xim, xub,
                                  W_re, W_im, (unsigned*)(ws + WS_WIB));
  k_xeig<<<768, 256, 0, stream>>>(xub, (const unsigned*)(ws + WS_WE),
                                  (const unsigned*)(ws + WS_SG),
                                  xeb, ws + WS_G1, sg_b1, ws + WS_PART);
  k_flux<<<1, 64, 0, stream>>>(ws, out, dt_seq, flux_re, flux_im, lam_flux,
                               bf_re, bf_im, c_re, c_im, g_w, g_b, a_decay, b_freq);
  k_gate<<<PIX / 128, 256, 0, stream>>>(ws + WS_G1, ws + WS_G2, sg_dw, sg_w2, sg_b2);
  k_scan<<<dim3(4096 / 256, 32, 2), 256, 0, stream>>>(xeb, ws + WS_G2,
                                                      ws + WS_GATE, ws + WS_SRCR, ws + WS_SRCI,
                                                      ws + WS_OFR, ws + WS_OFI,
                                                      ws + WS_ODR, ws + WS_ODI,
                                                      hre, him, out);
  k_final<<<768, 256, 0, stream>>>(xeb, xub, out, (const unsigned*)(ws + WS_WIB),
                                   ln_t_g, ln_t_b, ffn_w1, ffn_b1, ffn_w2, ffn_b2);
}